// Round 5
// baseline (1730.385 us; speedup 1.0000x reference)
//
#include <hip/hip_runtime.h>
#include <math.h>

// B=128, N=4096, Din=128, D=128, S(slots)=8, H=256, 3 iterations.
// Algebraic folds: logits = xn @ q2^T with q2 = slots_n @ Wqk, Wqk = scale*Wq^T@Wk.
// gx = raw @ Wihv^T with raw = attn^T @ xn (per-chunk partials), Wihv = Wih@Wv.
// R0: LN(x) fused into iter-0 attention. R2: MFMA PV (P^T hi/lo bf16 in LDS).
// R3: transposed logits + per-lane softmax + launch_bounds(256,4).
// R4: each iteration is ONE dispatch: attention blocks + tail-block slot update
//   (threadfence + atomicAdd ticket; 32nd block of a batch-pair runs the GRU/MLP
//   inline). Removes 6 launch/drain boundaries, hides the 64-block slot phase
//   under other batches' attention, and GRU gates now compute in registers
//   (GEMM1 wave->gate-triplet column mapping) - no 48KB gx/gh LDS round-trip.
// MFMA 16x16x32 bf16 layouts (verified):
//   C/D: col = lane&15, row = (lane>>4)*4 + reg
//   A  : A[m = lane&15][k = (lane>>4)*8 + j]
//   B  : B[k = (lane>>4)*8 + j][n = lane&15]  (row-major [N][K] source)

typedef __attribute__((ext_vector_type(4))) float fx4;
typedef __attribute__((ext_vector_type(8))) short sx8;
typedef __attribute__((ext_vector_type(4))) short sx4;
typedef __attribute__((ext_vector_type(8))) __bf16 bfx8;
typedef __attribute__((ext_vector_type(4))) unsigned short ux4;

static __device__ __forceinline__ fx4 MFMA(sx8 a, sx8 b, fx4 c) {
  return __builtin_amdgcn_mfma_f32_16x16x32_bf16(
      __builtin_bit_cast(bfx8, a), __builtin_bit_cast(bfx8, b), c, 0, 0, 0);
}

static __device__ __forceinline__ unsigned short f2bf(float f) {
  union { float f; unsigned u; } x; x.f = f;
  unsigned r = x.u + 0x7fffu + ((x.u >> 16) & 1u);  // RNE
  return (unsigned short)(r >> 16);
}
static __device__ __forceinline__ float bf2f(unsigned short u) {
  union { unsigned u; float f; } x; x.u = ((unsigned)u) << 16; return x.f;
}
static __device__ __forceinline__ fx4 ntload4(const float* p) {
  return __builtin_nontemporal_load((const fx4*)p);
}

#define PSTR 72
// LDS union: attn uses [0,34944): abuf 16384 | plds 18432 | sattnbuf 128
//            post uses [0,28992): xfr 4096 | hfr 4096 | ynf 4096 | y1f 8192 |
//                                 snew 8448 | satred 64
#define SMEM_BYTES 34944

// ---------------- fold: Wqk = scale*Wq^T@Wk (fp32), Wihv = Wih@Wv (fp32) -------------
__global__ __launch_bounds__(256) void k_fold(
    const float* __restrict__ Wq, const float* __restrict__ Wk,
    const float* __restrict__ Wih, const float* __restrict__ Wv,
    float* __restrict__ Wqk, float* __restrict__ Wihv) {
  int idx = blockIdx.x * 256 + threadIdx.x;
  if (idx < 16384) {
    int e = idx >> 7, c = idx & 127;
    float s = 0.f;
#pragma unroll 4
    for (int d = 0; d < 128; d++) s += Wq[d * 128 + e] * Wk[d * 128 + c];
    Wqk[idx] = s * 0.08838834764831845f;
    return;
  }
  idx -= 16384;
  if (idx < 49152) {
    int g = idx >> 7, c = idx & 127;
    float s = 0.f;
#pragma unroll 4
    for (int d = 0; d < 128; d++) s += Wih[g * 128 + d] * Wv[d * 128 + c];
    Wihv[idx] = s;
  }
}

// ---------------- pack: slots init + bf16 weight tables + counter zeroing ------------
__global__ __launch_bounds__(256) void k_pack(
    const float* __restrict__ noise, const float* __restrict__ mu,
    const float* __restrict__ lsig, const float* __restrict__ Wqk,
    const float* __restrict__ Wihv, const float* __restrict__ Whh,
    const float* __restrict__ W1, const float* __restrict__ W2,
    float* __restrict__ slots, unsigned short* __restrict__ wqk_b,
    unsigned short* __restrict__ wihv_b, unsigned short* __restrict__ whh_b,
    unsigned short* __restrict__ w1_b, unsigned short* __restrict__ w2_b,
    unsigned* __restrict__ cnt) {
  int idx = blockIdx.x * 256 + threadIdx.x;
  if (idx < 131072) {
    int d = idx & 127;
    slots[idx] = mu[d] + expf(lsig[d]) * noise[idx];
    return;
  }
  idx -= 131072;
  if (idx < 16384) {  // wqk_b row-major [n=c][k=e] <- Wqk[e,c]
    wqk_b[idx] = f2bf(Wqk[(idx & 127) * 128 + (idx >> 7)]);
    return;
  }
  idx -= 16384;
  if (idx < 49152) { wihv_b[idx] = f2bf(Wihv[idx]); return; }
  idx -= 49152;
  if (idx < 49152) { whh_b[idx] = f2bf(Whh[idx]); return; }
  idx -= 49152;
  if (idx < 32768) { w1_b[idx] = f2bf(W1[idx]); return; }
  idx -= 32768;
  if (idx < 32768) { w2_b[idx] = f2bf(W2[idx]); return; }
  idx -= 32768;
  if (idx < 192) cnt[idx] = 0;  // 3 iterations x 64 batch-pair counters
}

// ---------------- iter0 only: LN(slots) + q2 = slots_n @ Wqk ----------------
__global__ __launch_bounds__(64) void k_slot_pre(
    const float* __restrict__ slots, const unsigned short* __restrict__ wqk_b,
    float* __restrict__ slots_n, unsigned short* __restrict__ q2_b) {
  __shared__ __align__(16) short xf[4 * 64 * 8];
  int l = threadIdx.x;
  int r = l & 15, seg = l >> 4;
  long rowbase = (long)blockIdx.x * 16;
  {
    const float* xp = slots + (rowbase + r) * 128 + seg * 32;
    float* snp = slots_n + (rowbase + r) * 128 + seg * 32;
    float v[32];
    float s = 0.f, s2 = 0.f;
#pragma unroll
    for (int i = 0; i < 8; i++) {
      fx4 t = *(const fx4*)(xp + i * 4);
      v[i * 4 + 0] = t.x; v[i * 4 + 1] = t.y; v[i * 4 + 2] = t.z; v[i * 4 + 3] = t.w;
      s += t.x + t.y + t.z + t.w;
      s2 += t.x * t.x + t.y * t.y + t.z * t.z + t.w * t.w;
    }
    s += __shfl_xor(s, 16, 64);  s += __shfl_xor(s, 32, 64);
    s2 += __shfl_xor(s2, 16, 64); s2 += __shfl_xor(s2, 32, 64);
    float mean = s * 0.0078125f;
    float var = s2 * 0.0078125f - mean * mean;
    float rstd = rsqrtf(var + 1e-5f);
#pragma unroll
    for (int i = 0; i < 8; i++) {
      fx4 t = {(v[i * 4 + 0] - mean) * rstd, (v[i * 4 + 1] - mean) * rstd,
               (v[i * 4 + 2] - mean) * rstd, (v[i * 4 + 3] - mean) * rstd};
      *(fx4*)(snp + i * 4) = t;
      v[i * 4 + 0] = t.x; v[i * 4 + 1] = t.y; v[i * 4 + 2] = t.z; v[i * 4 + 3] = t.w;
    }
#pragma unroll
    for (int q = 0; q < 4; q++) {
      sx8 t;
#pragma unroll
      for (int j = 0; j < 8; j++) t[j] = (short)f2bf(v[q * 8 + j]);
      *(sx8*)&xf[(seg * 64 + (r + 16 * q)) * 8] = t;
    }
  }
  __syncthreads();
  const fx4 z4 = {0.f, 0.f, 0.f, 0.f};
  fx4 acc[8];
#pragma unroll
  for (int nt = 0; nt < 8; nt++) acc[nt] = z4;
#pragma unroll
  for (int ks = 0; ks < 4; ks++) {
    sx8 a = *(const sx8*)&xf[(ks * 64 + l) * 8];
#pragma unroll
    for (int nt = 0; nt < 8; nt++) {
      sx8 bfr = *(const sx8*)(wqk_b + (nt * 16 + (l & 15)) * 128 + ks * 32 + (l >> 4) * 8);
      acc[nt] = MFMA(a, bfr, acc[nt]);
    }
  }
  int cl = l & 15, rq = (l >> 4) * 4;
#pragma unroll
  for (int nt = 0; nt < 8; nt++)
#pragma unroll
    for (int rg = 0; rg < 4; rg++)
      q2_b[(rowbase + rq + rg) * 128 + nt * 16 + cl] = f2bf(acc[nt][rg]);
}

// ---------------- tail-block slot update (GRU + MLP + next LN/q2) ----------------
// Runs with 256 threads on LDS [0,28992). rowbase = 16 rows (2 batches).
static __device__ __forceinline__ void slot_post_body(
    char* smem, int tid, int rowbase,
    const float* __restrict__ upd_part, const float* __restrict__ sattn_part,
    float* __restrict__ slots_n,
    const unsigned short* __restrict__ wihv_b, const unsigned short* __restrict__ whh_b,
    const float* __restrict__ b_ih, const float* __restrict__ b_hh,
    const unsigned short* __restrict__ w1_b, const float* __restrict__ b1,
    const unsigned short* __restrict__ w2_b, const float* __restrict__ b2,
    const unsigned short* __restrict__ wqk_b, unsigned short* __restrict__ q2_b,
    float* __restrict__ out_final, int final_flag) {
  short* xfr = (short*)smem;                 // 4096
  short* hfr = (short*)(smem + 4096);        // 4096
  short* ynf = (short*)(smem + 8192);        // 4096
  short* y1f = (short*)(smem + 12288);       // 8192
  float* snew = (float*)(smem + 20480);      // 16*132*4 = 8448
  float* satred = (float*)(smem + 28928);    // 64
  int w = tid >> 6, l = tid & 63;
  int r = l & 15, seg = l >> 4;
  const fx4 z4 = {0.f, 0.f, 0.f, 0.f};
  {  // phase A: per-thread register accumulation over all 16 chunks
    int tr = tid & 15, tc = tid >> 4;
    int row = rowbase + tr;
    int bb = row >> 3, ss = row & 7;
    fx4 a0 = z4, a1 = z4;
#pragma unroll 4
    for (int ci = 0; ci < 16; ci++) {
      const float* up = upd_part + (size_t)(bb * 16 + ci) * 1024 + ss * 128 + tc * 8;
      a0 += *(const fx4*)up;
      a1 += *(const fx4*)(up + 4);
    }
    if (tc == 0) {
      float ssum = 0.f;
#pragma unroll 4
      for (int ci = 0; ci < 16; ci++) ssum += sattn_part[(bb * 16 + ci) * 8 + ss];
      satred[tr] = ssum;
    }
    {  // hfr: A-frag of slots_n
      const float* hp = slots_n + (long)row * 128 + tc * 8;
      fx4 t0 = *(const fx4*)hp, t1 = *(const fx4*)(hp + 4);
      sx8 t;
      t[0] = (short)f2bf(t0.x); t[1] = (short)f2bf(t0.y);
      t[2] = (short)f2bf(t0.z); t[3] = (short)f2bf(t0.w);
      t[4] = (short)f2bf(t1.x); t[5] = (short)f2bf(t1.y);
      t[6] = (short)f2bf(t1.z); t[7] = (short)f2bf(t1.w);
      int ks = tc >> 2, q = tc & 3;
      *(sx8*)&hfr[(ks * 64 + tr + 16 * q) * 8] = t;
    }
    __syncthreads();
    float inv = 1.f / satred[tr];
    sx8 t;
    t[0] = (short)f2bf(a0.x * inv); t[1] = (short)f2bf(a0.y * inv);
    t[2] = (short)f2bf(a0.z * inv); t[3] = (short)f2bf(a0.w * inv);
    t[4] = (short)f2bf(a1.x * inv); t[5] = (short)f2bf(a1.y * inv);
    t[6] = (short)f2bf(a1.z * inv); t[7] = (short)f2bf(a1.w * inv);
    int ks = tc >> 2, q = tc & 3;
    *(sx8*)&xfr[(ks * 64 + tr + 16 * q) * 8] = t;
  }
  __syncthreads();
  {  // GEMM1 with gate-triplet column mapping; GRU gates in registers
    fx4 ax[6], ah[6];
#pragma unroll
    for (int j = 0; j < 6; j++) { ax[j] = z4; ah[j] = z4; }
    int cl = l & 15;
#pragma unroll
    for (int ks = 0; ks < 4; ks++) {
      sx8 a_x = *(const sx8*)&xfr[(ks * 64 + l) * 8];
      sx8 a_h = *(const sx8*)&hfr[(ks * 64 + l) * 8];
#pragma unroll
      for (int j = 0; j < 6; j++) {
        int nt = w * 2 + (j & 1) + (j >> 1) * 8;  // {2w,2w+1,2w+8,2w+9,2w+16,2w+17}
        sx8 bx = *(const sx8*)(wihv_b + (nt * 16 + cl) * 128 + ks * 32 + seg * 8);
        sx8 bh = *(const sx8*)(whh_b + (nt * 16 + cl) * 128 + ks * 32 + seg * 8);
        ax[j] = MFMA(a_x, bx, ax[j]);
        ah[j] = MFMA(a_h, bh, ah[j]);
      }
    }
#pragma unroll
    for (int jj = 0; jj < 2; jj++) {
      int col = (w * 2 + jj) * 16 + cl;  // [0,128)
      float bir = b_ih[col], biz = b_ih[128 + col], bin = b_ih[256 + col];
      float bhr = b_hh[col], bhz = b_hh[128 + col], bhn = b_hh[256 + col];
#pragma unroll
      for (int rg = 0; rg < 4; rg++) {
        int row = seg * 4 + rg;
        float xr = ax[jj][rg] + bir, xz = ax[jj + 2][rg] + biz, xnn = ax[jj + 4][rg] + bin;
        float hr = ah[jj][rg] + bhr, hz = ah[jj + 2][rg] + bhz, hnn = ah[jj + 4][rg] + bhn;
        float rr = 1.f / (1.f + __expf(-(xr + hr)));
        float zz = 1.f / (1.f + __expf(-(xz + hz)));
        float nn = tanhf(xnn + rr * hnn);
        float h = slots_n[(long)(rowbase + row) * 128 + col];
        snew[row * 132 + col] = (1.f - zz) * nn + zz * h;
      }
    }
  }
  __syncthreads();
  if (w == 0) {  // LN(snew) -> ynf A-frags
    float v[32];
    float s = 0.f, s2 = 0.f;
#pragma unroll
    for (int i = 0; i < 32; i++) {
      float t = snew[r * 132 + seg * 32 + i];
      v[i] = t; s += t; s2 += t * t;
    }
    s += __shfl_xor(s, 16, 64);  s += __shfl_xor(s, 32, 64);
    s2 += __shfl_xor(s2, 16, 64); s2 += __shfl_xor(s2, 32, 64);
    float mean = s * 0.0078125f;
    float var = s2 * 0.0078125f - mean * mean;
    float rstd = rsqrtf(var + 1e-5f);
#pragma unroll
    for (int q = 0; q < 4; q++) {
      sx8 t;
#pragma unroll
      for (int j = 0; j < 8; j++) t[j] = (short)f2bf((v[q * 8 + j] - mean) * rstd);
      *(sx8*)&ynf[(seg * 64 + (r + 16 * q)) * 8] = t;
    }
  }
  __syncthreads();
  {  // GEMM2: y1 = relu(LN@W1^T + b1) -> A-frags for GEMM3
    fx4 y[4];
#pragma unroll
    for (int j = 0; j < 4; j++) y[j] = z4;
#pragma unroll
    for (int ks = 0; ks < 4; ks++) {
      sx8 a = *(const sx8*)&ynf[(ks * 64 + l) * 8];
#pragma unroll
      for (int j = 0; j < 4; j++) {
        int nt = w * 4 + j;
        sx8 bf = *(const sx8*)(w1_b + (nt * 16 + (l & 15)) * 128 + ks * 32 + (l >> 4) * 8);
        y[j] = MFMA(a, bf, y[j]);
      }
    }
#pragma unroll
    for (int j = 0; j < 4; j++) {
      int col = (w * 4 + j) * 16 + (l & 15);
      float bias = b1[col];
      int ks3 = col >> 5, qq = (col >> 3) & 3, jj = col & 7;
#pragma unroll
      for (int rg = 0; rg < 4; rg++) {
        float val = fmaxf(y[j][rg] + bias, 0.f);
        int m = (l >> 4) * 4 + rg;
        y1f[(ks3 * 64 + m + 16 * qq) * 8 + jj] = (short)f2bf(val);
      }
    }
  }
  __syncthreads();
  {  // GEMM3: snew += y1@W2^T + b2
    fx4 zz2[2];
    zz2[0] = z4; zz2[1] = z4;
#pragma unroll
    for (int ks = 0; ks < 8; ks++) {
      sx8 a = *(const sx8*)&y1f[(ks * 64 + l) * 8];
#pragma unroll
      for (int j = 0; j < 2; j++) {
        sx8 bf = *(const sx8*)(w2_b + ((w * 2 + j) * 16 + (l & 15)) * 256 + ks * 32 + (l >> 4) * 8);
        zz2[j] = MFMA(a, bf, zz2[j]);
      }
    }
#pragma unroll
    for (int j = 0; j < 2; j++) {
      int col = (w * 2 + j) * 16 + (l & 15);
      float bias = b2[col];
#pragma unroll
      for (int rg = 0; rg < 4; rg++) {
        int row = (l >> 4) * 4 + rg;
        snew[row * 132 + col] += zz2[j][rg] + bias;
      }
    }
  }
  __syncthreads();
  if (final_flag) {
    int row = tid >> 4, c8 = (tid & 15) * 8;
    fx4 t0 = *(const fx4*)&snew[row * 132 + c8];
    fx4 t1 = *(const fx4*)&snew[row * 132 + c8 + 4];
    *(fx4*)(out_final + (long)(rowbase + row) * 128 + c8) = t0;
    *(fx4*)(out_final + (long)(rowbase + row) * 128 + c8 + 4) = t1;
    return;
  }
  // fused next-iter: LN(new slots) -> slots_n + q2
  if (w == 0) {
    float v[32];
    float s = 0.f, s2 = 0.f;
#pragma unroll
    for (int i = 0; i < 32; i++) {
      float t = snew[r * 132 + seg * 32 + i];
      v[i] = t; s += t; s2 += t * t;
    }
    s += __shfl_xor(s, 16, 64);  s += __shfl_xor(s, 32, 64);
    s2 += __shfl_xor(s2, 16, 64); s2 += __shfl_xor(s2, 32, 64);
    float mean = s * 0.0078125f;
    float var = s2 * 0.0078125f - mean * mean;
    float rstd = rsqrtf(var + 1e-5f);
    float* snp = slots_n + (long)(rowbase + r) * 128 + seg * 32;
#pragma unroll
    for (int i = 0; i < 8; i++) {
      fx4 t = {(v[i * 4 + 0] - mean) * rstd, (v[i * 4 + 1] - mean) * rstd,
               (v[i * 4 + 2] - mean) * rstd, (v[i * 4 + 3] - mean) * rstd};
      *(fx4*)(snp + i * 4) = t;
      v[i * 4 + 0] = t.x; v[i * 4 + 1] = t.y; v[i * 4 + 2] = t.z; v[i * 4 + 3] = t.w;
    }
#pragma unroll
    for (int q = 0; q < 4; q++) {
      sx8 t;
#pragma unroll
      for (int j = 0; j < 8; j++) t[j] = (short)f2bf(v[q * 8 + j]);
      *(sx8*)&ynf[(seg * 64 + (r + 16 * q)) * 8] = t;
    }
  }
  __syncthreads();
  {  // q2 GEMM: wave w computes nt = w*2, w*2+1
    fx4 acc2[2];
    acc2[0] = z4; acc2[1] = z4;
#pragma unroll
    for (int ks = 0; ks < 4; ks++) {
      sx8 a = *(const sx8*)&ynf[(ks * 64 + l) * 8];
#pragma unroll
      for (int j = 0; j < 2; j++) {
        int nt = w * 2 + j;
        sx8 bf = *(const sx8*)(wqk_b + (nt * 16 + (l & 15)) * 128 + ks * 32 + (l >> 4) * 8);
        acc2[j] = MFMA(a, bf, acc2[j]);
      }
    }
    int cl = l & 15, rq = (l >> 4) * 4;
#pragma unroll
    for (int j = 0; j < 2; j++) {
      int nt = w * 2 + j;
#pragma unroll
      for (int rg = 0; rg < 4; rg++)
        q2_b[(long)(rowbase + rq + rg) * 128 + nt * 16 + cl] = f2bf(acc2[j][rg]);
    }
  }
}

// ---------------- fused iteration: attention + tail-block slot update ----------------
__global__ __launch_bounds__(256, 4) void k_iter(
    const unsigned short* __restrict__ ln16, const unsigned short* __restrict__ q2b,
    float* __restrict__ upd_part, float* __restrict__ sattn_part,
    unsigned* __restrict__ pcnt,
    float* __restrict__ slots_n,
    const unsigned short* __restrict__ wihv_b, const unsigned short* __restrict__ whh_b,
    const float* __restrict__ b_ih, const float* __restrict__ b_hh,
    const unsigned short* __restrict__ w1_b, const float* __restrict__ b1,
    const unsigned short* __restrict__ w2_b, const float* __restrict__ b2,
    const unsigned short* __restrict__ wqk_b, unsigned short* __restrict__ q2_b,
    float* __restrict__ out_final, int final_flag) {
  __shared__ __align__(16) char smem[SMEM_BYTES];
  __shared__ unsigned tail_done;
  float* abuf = (float*)smem;
  short* pbase = (short*)(smem + 16384);
  float* sattnbuf = (float*)(smem + 16384 + 18432);
  int tid = threadIdx.x, w = tid >> 6, l = tid & 63;
  int b = blockIdx.x >> 4, c = blockIdx.x & 15;
  long base = (long)b * 4096 + (c * 4 + w) * 64;
  const unsigned short* xt = ln16 + base * 128;
  int nr = l & 15, seg = l >> 4, qd = seg * 8;
  sx8 qf[4];
#pragma unroll
  for (int ks = 0; ks < 4; ks++) {
    if (nr < 8) {
      qf[ks] = *(const sx8*)(q2b + ((long)b * 8 + nr) * 128 + ks * 32 + qd);
    } else {
      sx8 t;
#pragma unroll
      for (int j = 0; j < 8; j++) t[j] = 0;
      qf[ks] = t;
    }
  }
  const fx4 z4 = {0.f, 0.f, 0.f, 0.f};
  float satacc[4] = {0.f, 0.f, 0.f, 0.f};
  short* ph = pbase + (w * 2) * (16 * PSTR);
  short* pl = pbase + (w * 2 + 1) * (16 * PSTR);
#pragma unroll
  for (int mt = 0; mt < 4; mt++) {
    fx4 cc = z4;
#pragma unroll
    for (int ks = 0; ks < 4; ks++) {
      sx8 bfr = *(const sx8*)(xt + (mt * 16 + nr) * 128 + ks * 32 + qd);
      cc = MFMA(qf[ks], bfr, cc);
    }
    float m01 = fmaxf(fmaxf(cc[0], cc[1]), fmaxf(cc[2], cc[3]));
    m01 = fmaxf(m01, __shfl_xor(m01, 16, 64));
    float p0 = __expf(cc[0] - m01), p1 = __expf(cc[1] - m01),
          p2 = __expf(cc[2] - m01), p3 = __expf(cc[3] - m01);
    float sl = p0 + p1 + p2 + p3;
    sl += __shfl_xor(sl, 16, 64);
    float inv = 1.f / sl;
    float at0 = p0 * inv + 1e-8f, at1 = p1 * inv + 1e-8f;
    float at2 = p2 * inv + 1e-8f, at3 = p3 * inv + 1e-8f;
    satacc[0] += at0; satacc[1] += at1; satacc[2] += at2; satacc[3] += at3;
    int pb = mt * 16 + nr;
    unsigned short h0 = f2bf(at0), h1 = f2bf(at1), h2 = f2bf(at2), h3 = f2bf(at3);
    ph[(seg * 4 + 0) * PSTR + pb] = (short)h0;
    ph[(seg * 4 + 1) * PSTR + pb] = (short)h1;
    ph[(seg * 4 + 2) * PSTR + pb] = (short)h2;
    ph[(seg * 4 + 3) * PSTR + pb] = (short)h3;
    pl[(seg * 4 + 0) * PSTR + pb] = (short)f2bf(at0 - bf2f(h0));
    pl[(seg * 4 + 1) * PSTR + pb] = (short)f2bf(at1 - bf2f(h1));
    pl[(seg * 4 + 2) * PSTR + pb] = (short)f2bf(at2 - bf2f(h2));
    pl[(seg * 4 + 3) * PSTR + pb] = (short)f2bf(at3 - bf2f(h3));
  }
  fx4 acc[8];
#pragma unroll
  for (int nt = 0; nt < 8; nt++) acc[nt] = z4;
#pragma unroll
  for (int ks2 = 0; ks2 < 2; ks2++) {
    sx8 pah = *(const sx8*)&ph[nr * PSTR + ks2 * 32 + seg * 8];
    sx8 pal = *(const sx8*)&pl[nr * PSTR + ks2 * 32 + seg * 8];
#pragma unroll
    for (int nt = 0; nt < 8; nt++) {
      const unsigned short* cp = xt + (ks2 * 32 + seg * 8) * 128 + nt * 16 + nr;
      sx8 bfr;
#pragma unroll
      for (int j = 0; j < 8; j++) bfr[j] = (short)cp[j * 128];
      acc[nt] = MFMA(pah, bfr, acc[nt]);
      acc[nt] = MFMA(pal, bfr, acc[nt]);
    }
  }
  if (seg < 2) {
#pragma unroll
    for (int nt = 0; nt < 8; nt++)
#pragma unroll
      for (int rg = 0; rg < 4; rg++)
        abuf[w * 1024 + (seg * 4 + rg) * 128 + nt * 16 + nr] = acc[nt][rg];
  }
#pragma unroll
  for (int rg = 0; rg < 4; rg++) {
    float v = satacc[rg];
    v += __shfl_xor(v, 1, 64);
    v += __shfl_xor(v, 2, 64);
    v += __shfl_xor(v, 4, 64);
    v += __shfl_xor(v, 8, 64);
    if (nr == 0 && seg < 2) sattnbuf[w * 8 + seg * 4 + rg] = v;
  }
  __syncthreads();
  {
    int i = tid * 4;
    fx4 o = *(const fx4*)&abuf[i] + *(const fx4*)&abuf[1024 + i] +
            *(const fx4*)&abuf[2048 + i] + *(const fx4*)&abuf[3072 + i];
    *(fx4*)(upd_part + ((size_t)(b * 16 + c)) * 1024 + i) = o;
    if (tid < 8)
      sattn_part[(b * 16 + c) * 8 + tid] =
          sattnbuf[tid] + sattnbuf[8 + tid] + sattnbuf[16 + tid] + sattnbuf[24 + tid];
  }
  // ---- tail-block ticket: last of the batch-pair runs the slot update ----
  __threadfence();
  if (tid == 0) tail_done = (atomicAdd(&pcnt[b >> 1], 1u) == 31u) ? 1u : 0u;
  __syncthreads();
  if (!tail_done) return;
  __threadfence();
  slot_post_body(smem, tid, (b >> 1) * 16, upd_part, sattn_part, slots_n,
                 wihv_b, whh_b, b_ih, b_hh, w1_b, b1, w2_b, b2, wqk_b, q2_b,
                 out_final, final_flag);
}

// ---------------- fused iteration 0: LN(x) + attention + tail slot update ------------
__global__ __launch_bounds__(256, 4) void k_iter_first(
    const float* __restrict__ x, unsigned short* __restrict__ ln16,
    const unsigned short* __restrict__ q2b,
    float* __restrict__ upd_part, float* __restrict__ sattn_part,
    unsigned* __restrict__ pcnt,
    float* __restrict__ slots_n,
    const unsigned short* __restrict__ wihv_b, const unsigned short* __restrict__ whh_b,
    const float* __restrict__ b_ih, const float* __restrict__ b_hh,
    const unsigned short* __restrict__ w1_b, const float* __restrict__ b1,
    const unsigned short* __restrict__ w2_b, const float* __restrict__ b2,
    const unsigned short* __restrict__ wqk_b, unsigned short* __restrict__ q2_b,
    float* __restrict__ out_final, int final_flag) {
  __shared__ __align__(16) char smem[SMEM_BYTES];
  __shared__ unsigned tail_done;
  float* abuf = (float*)smem;
  short* pbase = (short*)(smem + 16384);
  float* sattnbuf = (float*)(smem + 16384 + 18432);
  int tid = threadIdx.x, w = tid >> 6, l = tid & 63;
  int b = blockIdx.x >> 4, c = blockIdx.x & 15;
  long base = (long)b * 4096 + (c * 4 + w) * 64;
  const float* xs = x + base * 128;
  unsigned short* xt = ln16 + base * 128;
  int nr = l & 15, seg = l >> 4, qd = seg * 8;
  sx8 qf[4];
#pragma unroll
  for (int ks = 0; ks < 4; ks++) {
    if (nr < 8) {
      qf[ks] = *(const sx8*)(q2b + ((long)b * 8 + nr) * 128 + ks * 32 + qd);
    } else {
      sx8 t;
#pragma unroll
      for (int j = 0; j < 8; j++) t[j] = 0;
      qf[ks] = t;
    }
  }
  const fx4 z4 = {0.f, 0.f, 0.f, 0.f};
  float satacc[4] = {0.f, 0.f, 0.f, 0.f};
  short* ph = pbase + (w * 2) * (16 * PSTR);
  short* pl = pbase + (w * 2 + 1) * (16 * PSTR);
#pragma unroll
  for (int mt = 0; mt < 4; mt++) {
    const float* rp = xs + (mt * 16 + nr) * 128 + qd;
    float v[32];
    float sm = 0.f, s2 = 0.f;
#pragma unroll
    for (int ks = 0; ks < 4; ks++) {
      fx4 t0 = ntload4(rp + ks * 32);
      fx4 t1 = ntload4(rp + ks * 32 + 4);
      v[ks * 8 + 0] = t0.x; v[ks * 8 + 1] = t0.y; v[ks * 8 + 2] = t0.z; v[ks * 8 + 3] = t0.w;
      v[ks * 8 + 4] = t1.x; v[ks * 8 + 5] = t1.y; v[ks * 8 + 6] = t1.z; v[ks * 8 + 7] = t1.w;
      sm += t0.x + t0.y + t0.z + t0.w + t1.x + t1.y + t1.z + t1.w;
      s2 += t0.x * t0.x + t0.y * t0.y + t0.z * t0.z + t0.w * t0.w +
            t1.x * t1.x + t1.y * t1.y + t1.z * t1.z + t1.w * t1.w;
    }
    sm += __shfl_xor(sm, 16, 64);  sm += __shfl_xor(sm, 32, 64);
    s2 += __shfl_xor(s2, 16, 64);  s2 += __shfl_xor(s2, 32, 64);
    float mean = sm * 0.0078125f;
    float rstd = rsqrtf(s2 * 0.0078125f - mean * mean + 1e-5f);
    fx4 cc = z4;
#pragma unroll
    for (int ks = 0; ks < 4; ks++) {
      sx8 t;
#pragma unroll
      for (int j = 0; j < 8; j++) t[j] = (short)f2bf((v[ks * 8 + j] - mean) * rstd);
      *(sx8*)(xt + (mt * 16 + nr) * 128 + ks * 32 + qd) = t;
      cc = MFMA(qf[ks], t, cc);
    }
    float m01 = fmaxf(fmaxf(cc[0], cc[1]), fmaxf(cc[2], cc[3]));
    m01 = fmaxf(m01, __shfl_xor(m01, 16, 64));
    float p0 = __expf(cc[0] - m01), p1 = __expf(cc[1] - m01),
          p2 = __expf(cc[2] - m01), p3 = __expf(cc[3] - m01);
    float sl = p0 + p1 + p2 + p3;
    sl += __shfl_xor(sl, 16, 64);
    float inv = 1.f / sl;
    float at0 = p0 * inv + 1e-8f, at1 = p1 * inv + 1e-8f;
    float at2 = p2 * inv + 1e-8f, at3 = p3 * inv + 1e-8f;
    satacc[0] += at0; satacc[1] += at1; satacc[2] += at2; satacc[3] += at3;
    int pb = mt * 16 + nr;
    unsigned short h0 = f2bf(at0), h1 = f2bf(at1), h2 = f2bf(at2), h3 = f2bf(at3);
    ph[(seg * 4 + 0) * PSTR + pb] = (short)h0;
    ph[(seg * 4 + 1) * PSTR + pb] = (short)h1;
    ph[(seg * 4 + 2) * PSTR + pb] = (short)h2;
    ph[(seg * 4 + 3) * PSTR + pb] = (short)h3;
    pl[(seg * 4 + 0) * PSTR + pb] = (short)f2bf(at0 - bf2f(h0));
    pl[(seg * 4 + 1) * PSTR + pb] = (short)f2bf(at1 - bf2f(h1));
    pl[(seg * 4 + 2) * PSTR + pb] = (short)f2bf(at2 - bf2f(h2));
    pl[(seg * 4 + 3) * PSTR + pb] = (short)f2bf(at3 - bf2f(h3));
  }
  __threadfence_block();
  fx4 acc[8];
#pragma unroll
  for (int nt = 0; nt < 8; nt++) acc[nt] = z4;
#pragma unroll
  for (int ks2 = 0; ks2 < 2; ks2++) {
    sx8 pah = *(const sx8*)&ph[nr * PSTR + ks2 * 32 + seg * 8];
    sx8 pal = *(const sx8*)&pl[nr * PSTR + ks2 * 32 + seg * 8];
#pragma unroll
    for (int nt = 0; nt < 8; nt++) {
      const unsigned short* cp = xt + (ks2 * 32 + seg * 8) * 128 + nt * 16 + nr;
      sx8 bfr;
#pragma unroll
      for (int j = 0; j < 8; j++) bfr[j] = (short)cp[j * 128];
      acc[nt] = MFMA(pah, bfr, acc[nt]);
      acc[nt] = MFMA(pal, bfr, acc[nt]);
    }
  }
  if (seg < 2) {
#pragma unroll
    for (int nt = 0; nt < 8; nt++)
#pragma unroll
      for (int rg = 0; rg < 4; rg++)
        abuf[w * 1024 + (seg * 4 + rg) * 128 + nt * 16 + nr] = acc[nt][rg];
  }
#pragma unroll
  for (int rg = 0; rg < 4; rg++) {
    float v = satacc[rg];
    v += __shfl_xor(v, 1, 64);
    v += __shfl_xor(v, 2, 64);
    v += __shfl_xor(v, 4, 64);
    v += __shfl_xor(v, 8, 64);
    if (nr == 0 && seg < 2) sattnbuf[w * 8 + seg * 4 + rg] = v;
  }
  __syncthreads();
  {
    int i = tid * 4;
    fx4 o = *(const fx4*)&abuf[i] + *(const fx4*)&abuf[1024 + i] +
            *(const fx4*)&abuf[2048 + i] + *(const fx4*)&abuf[3072 + i];
    *(fx4*)(upd_part + ((size_t)(b * 16 + c)) * 1024 + i) = o;
    if (tid < 8)
      sattn_part[(b * 16 + c) * 8 + tid] =
          sattnbuf[tid] + sattnbuf[8 + tid] + sattnbuf[16 + tid] + sattnbuf[24 + tid];
  }
  __threadfence();
  if (tid == 0) tail_done = (atomicAdd(&pcnt[b >> 1], 1u) == 31u) ? 1u : 0u;
  __syncthreads();
  if (!tail_done) return;
  __threadfence();
  slot_post_body(smem, tid, (b >> 1) * 16, upd_part, sattn_part, slots_n,
                 wihv_b, whh_b, b_ih, b_hh, w1_b, b1, w2_b, b2, wqk_b, q2_b,
                 out_final, final_flag);
}

extern "C" void kernel_launch(void* const* d_in, const int* in_sizes, int n_in,
                              void* d_out, int out_size, void* d_ws, size_t ws_size,
                              hipStream_t stream) {
  (void)in_sizes; (void)n_in; (void)out_size; (void)ws_size;
  const float* x = (const float*)d_in[0];
  const float* noise = (const float*)d_in[1];
  const float* mu = (const float*)d_in[2];
  const float* lsig = (const float*)d_in[3];
  const float* Wq = (const float*)d_in[4];
  const float* Wk = (const float*)d_in[5];
  const float* Wv = (const float*)d_in[6];
  const float* Wih = (const float*)d_in[7];
  const float* Whh = (const float*)d_in[8];
  const float* b_ih = (const float*)d_in[9];
  const float* b_hh = (const float*)d_in[10];
  const float* W1 = (const float*)d_in[11];
  const float* b1 = (const float*)d_in[12];
  const float* W2 = (const float*)d_in[13];
  const float* b2 = (const float*)d_in[14];

  char* ws = (char*)d_ws;
  size_t off = 0;
  auto take = [&](size_t bytes) {
    char* p = ws + off;
    off += (bytes + 255) & ~(size_t)255;
    return p;
  };
  unsigned short* ln16 = (unsigned short*)take(134217728);  // LN(x) bf16 row-major
  float* Wqk = (float*)take(65536);
  float* Wihv = (float*)take(196608);
  unsigned short* wqk_b = (unsigned short*)take(32768);
  unsigned short* wihv_b = (unsigned short*)take(98304);
  unsigned short* whh_b = (unsigned short*)take(98304);
  unsigned short* w1_b = (unsigned short*)take(65536);
  unsigned short* w2_b = (unsigned short*)take(65536);
  float* slots = (float*)take(524288);
  float* slots_n = (float*)take(524288);
  unsigned short* q2_b = (unsigned short*)take(262144);
  float* upd_part = (float*)take(8388608);    // raw partials (B,16,8,128) fp32
  float* sattn_part = (float*)take(65536);
  unsigned* cnt = (unsigned*)take(1024);      // 3 x 64 batch-pair tickets

  k_fold<<<256, 256, 0, stream>>>(Wq, Wk, Wih, Wv, Wqk, Wihv);
  k_pack<<<1217, 256, 0, stream>>>(noise, mu, lsig, Wqk, Wihv, Whh, W1, W2,
                                   slots, wqk_b, wihv_b, whh_b, w1_b, w2_b, cnt);
  k_slot_pre<<<64, 64, 0, stream>>>(slots, wqk_b, slots_n, q2_b);
  k_iter_first<<<2048, 256, 0, stream>>>(x, ln16, q2_b, upd_part, sattn_part,
                                         cnt, slots_n, wihv_b, whh_b, b_ih, b_hh,
                                         w1_b, b1, w2_b, b2, wqk_b, q2_b,
                                         (float*)d_out, 0);
  k_iter<<<2048, 256, 0, stream>>>(ln16, q2_b, upd_part, sattn_part,
                                   cnt + 64, slots_n, wihv_b, whh_b, b_ih, b_hh,
                                   w1_b, b1, w2_b, b2, wqk_b, q2_b,
                                   (float*)d_out, 0);
  k_iter<<<2048, 256, 0, stream>>>(ln16, q2_b, upd_part, sattn_part,
                                   cnt + 128, slots_n, wihv_b, whh_b, b_ih, b_hh,
                                   w1_b, b1, w2_b, b2, wqk_b, q2_b,
                                   (float*)d_out, 1);
}

// Round 6
// 708.497 us; speedup vs baseline: 2.4423x; 2.4423x over previous
//
#include <hip/hip_runtime.h>
#include <math.h>

// B=128, N=4096, Din=128, D=128, S(slots)=8, H=256, 3 iterations.
// Algebraic folds: logits = xn @ q2^T with q2 = slots_n @ Wqk, Wqk = scale*Wq^T@Wk.
// gx = raw @ Wihv^T with raw = attn^T @ xn (per-chunk partials), Wihv = Wih@Wv.
// k and v are never materialized; only ln_x (bf16, row-major) is stored.
// R0: LN(x) fused into iter-0 attention (k_attn_first), k_ln eliminated.
// R2: PV step via MFMA with P^T hi/lo bf16 split staged in LDS.
// R3: transposed logits + per-lane softmax.
// R4 (REVERTED): tail-block fusion. Per-block __threadfence() on non-coherent
//   per-XCD L2s forced device-scope writebacks; 2048 flushes destroyed cache
//   reuse -> 560 GB/s HBM-bound, 650us/dispatch. Stream ordering is cheaper.
// R5: LDS overlay — abuf[w] reuses plds[w] (wave reads its P^T fully before
//   writing raw partials). LDS 34.9KB -> 18.6KB => 8 blocks/CU (was 4),
//   2x resident waves to hide global-load latency in the latency-bound attn.
// MFMA 16x16x32 bf16 layouts (verified):
//   C/D: col = lane&15, row = (lane>>4)*4 + reg
//   A  : A[m = lane&15][k = (lane>>4)*8 + j]
//   B  : B[k = (lane>>4)*8 + j][n = lane&15]  (row-major [N][K] source)

typedef __attribute__((ext_vector_type(4))) float fx4;
typedef __attribute__((ext_vector_type(8))) short sx8;
typedef __attribute__((ext_vector_type(4))) short sx4;
typedef __attribute__((ext_vector_type(8))) __bf16 bfx8;
typedef __attribute__((ext_vector_type(4))) unsigned short ux4;

static __device__ __forceinline__ fx4 MFMA(sx8 a, sx8 b, fx4 c) {
  return __builtin_amdgcn_mfma_f32_16x16x32_bf16(
      __builtin_bit_cast(bfx8, a), __builtin_bit_cast(bfx8, b), c, 0, 0, 0);
}

static __device__ __forceinline__ unsigned short f2bf(float f) {
  union { float f; unsigned u; } x; x.f = f;
  unsigned r = x.u + 0x7fffu + ((x.u >> 16) & 1u);  // RNE
  return (unsigned short)(r >> 16);
}
static __device__ __forceinline__ float bf2f(unsigned short u) {
  union { unsigned u; float f; } x; x.u = ((unsigned)u) << 16; return x.f;
}
static __device__ __forceinline__ fx4 ntload4(const float* p) {
  return __builtin_nontemporal_load((const fx4*)p);
}

// P^T LDS plane stride (elements). Per-wave region = 2 planes * 16*PSTR shorts
// = 4608 B, which also hosts that wave's 4096 B raw-partial overlay after PV.
#define PSTR 72
#define WREG (2 * 16 * PSTR)  // shorts per wave region = 2304 (4608 B)

// ---------------- fold: Wqk = scale*Wq^T@Wk (fp32), Wihv = Wih@Wv (fp32) -------------
__global__ __launch_bounds__(256) void k_fold(
    const float* __restrict__ Wq, const float* __restrict__ Wk,
    const float* __restrict__ Wih, const float* __restrict__ Wv,
    float* __restrict__ Wqk, float* __restrict__ Wihv) {
  int idx = blockIdx.x * 256 + threadIdx.x;
  if (idx < 16384) {  // Wqk[e,c] = scale * sum_d Wq[d,e]*Wk[d,c]
    int e = idx >> 7, c = idx & 127;
    float s = 0.f;
#pragma unroll 4
    for (int d = 0; d < 128; d++) s += Wq[d * 128 + e] * Wk[d * 128 + c];
    Wqk[idx] = s * 0.08838834764831845f;
    return;
  }
  idx -= 16384;
  if (idx < 49152) {  // Wihv[g,c] = sum_d Wih[g,d]*Wv[d,c]
    int g = idx >> 7, c = idx & 127;
    float s = 0.f;
#pragma unroll 4
    for (int d = 0; d < 128; d++) s += Wih[g * 128 + d] * Wv[d * 128 + c];
    Wihv[idx] = s;
  }
}

// ---------------- pack: slots init + bf16 weight tables ----------------
__global__ __launch_bounds__(256) void k_pack(
    const float* __restrict__ noise, const float* __restrict__ mu,
    const float* __restrict__ lsig, const float* __restrict__ Wqk,
    const float* __restrict__ Wihv, const float* __restrict__ Whh,
    const float* __restrict__ W1, const float* __restrict__ W2,
    float* __restrict__ slots, unsigned short* __restrict__ wqk_b,
    unsigned short* __restrict__ wihv_b, unsigned short* __restrict__ whh_b,
    unsigned short* __restrict__ w1_b, unsigned short* __restrict__ w2_b) {
  int idx = blockIdx.x * 256 + threadIdx.x;
  if (idx < 131072) {
    int d = idx & 127;
    slots[idx] = mu[d] + expf(lsig[d]) * noise[idx];
    return;
  }
  idx -= 131072;
  if (idx < 16384) {  // wqk_b row-major [n=c][k=e] <- Wqk[e,c]
    wqk_b[idx] = f2bf(Wqk[(idx & 127) * 128 + (idx >> 7)]);
    return;
  }
  idx -= 16384;
  if (idx < 49152) { wihv_b[idx] = f2bf(Wihv[idx]); return; }
  idx -= 49152;
  if (idx < 49152) { whh_b[idx] = f2bf(Whh[idx]); return; }
  idx -= 49152;
  if (idx < 32768) { w1_b[idx] = f2bf(W1[idx]); return; }
  idx -= 32768;
  w2_b[idx] = f2bf(W2[idx]);
}

// ---------------- iter0 only: LN(slots) + q2 = slots_n @ Wqk ----------------
__global__ __launch_bounds__(64) void k_slot_pre(
    const float* __restrict__ slots, const unsigned short* __restrict__ wqk_b,
    float* __restrict__ slots_n, unsigned short* __restrict__ q2_b) {
  __shared__ __align__(16) short xf[4 * 64 * 8];
  int l = threadIdx.x;
  int r = l & 15, seg = l >> 4;
  long rowbase = (long)blockIdx.x * 16;
  {
    const float* xp = slots + (rowbase + r) * 128 + seg * 32;
    float* snp = slots_n + (rowbase + r) * 128 + seg * 32;
    float v[32];
    float s = 0.f, s2 = 0.f;
#pragma unroll
    for (int i = 0; i < 8; i++) {
      fx4 t = *(const fx4*)(xp + i * 4);
      v[i * 4 + 0] = t.x; v[i * 4 + 1] = t.y; v[i * 4 + 2] = t.z; v[i * 4 + 3] = t.w;
      s += t.x + t.y + t.z + t.w;
      s2 += t.x * t.x + t.y * t.y + t.z * t.z + t.w * t.w;
    }
    s += __shfl_xor(s, 16, 64);  s += __shfl_xor(s, 32, 64);
    s2 += __shfl_xor(s2, 16, 64); s2 += __shfl_xor(s2, 32, 64);
    float mean = s * 0.0078125f;
    float var = s2 * 0.0078125f - mean * mean;
    float rstd = rsqrtf(var + 1e-5f);
#pragma unroll
    for (int i = 0; i < 8; i++) {
      fx4 t = {(v[i * 4 + 0] - mean) * rstd, (v[i * 4 + 1] - mean) * rstd,
               (v[i * 4 + 2] - mean) * rstd, (v[i * 4 + 3] - mean) * rstd};
      *(fx4*)(snp + i * 4) = t;
      v[i * 4 + 0] = t.x; v[i * 4 + 1] = t.y; v[i * 4 + 2] = t.z; v[i * 4 + 3] = t.w;
    }
#pragma unroll
    for (int q = 0; q < 4; q++) {
      sx8 t;
#pragma unroll
      for (int j = 0; j < 8; j++) t[j] = (short)f2bf(v[q * 8 + j]);
      *(sx8*)&xf[(seg * 64 + (r + 16 * q)) * 8] = t;
    }
  }
  __syncthreads();
  const fx4 z4 = {0.f, 0.f, 0.f, 0.f};
  fx4 acc[8];
#pragma unroll
  for (int nt = 0; nt < 8; nt++) acc[nt] = z4;
#pragma unroll
  for (int ks = 0; ks < 4; ks++) {
    sx8 a = *(const sx8*)&xf[(ks * 64 + l) * 8];
#pragma unroll
    for (int nt = 0; nt < 8; nt++) {
      sx8 bfr = *(const sx8*)(wqk_b + (nt * 16 + (l & 15)) * 128 + ks * 32 + (l >> 4) * 8);
      acc[nt] = MFMA(a, bfr, acc[nt]);
    }
  }
  int cl = l & 15, rq = (l >> 4) * 4;
#pragma unroll
  for (int nt = 0; nt < 8; nt++)
#pragma unroll
    for (int rg = 0; rg < 4; rg++)
      q2_b[(rowbase + rq + rg) * 128 + nt * 16 + cl] = f2bf(acc[nt][rg]);
}

// ---------------- attention: logits^T = q2@xn^T, per-lane softmax, MFMA PV -------
// grid = 128 batches * 16 chunks = 2048 blocks, 256 thr; 1 tile of 64 rows per wave.
// LDS: plds[4 waves][2 planes][16*PSTR] (P^T hi/lo); after PV each wave overlays
// its 8x128 raw partial (fp32) onto its own region. 18.6 KB -> 8 blocks/CU.
__global__ __launch_bounds__(256, 8) void k_attn(
    const unsigned short* __restrict__ ln16, const unsigned short* __restrict__ q2b,
    float* __restrict__ upd_part, float* __restrict__ sattn_part) {
  __shared__ __align__(16) short plds[4 * WREG];
  __shared__ float sattnbuf[4 * 8];
  int tid = threadIdx.x, w = tid >> 6, l = tid & 63;
  int b = blockIdx.x >> 4, c = blockIdx.x & 15;
  long base = (long)b * 4096 + (c * 4 + w) * 64;
  const unsigned short* xt = ln16 + base * 128;
  int nr = l & 15, seg = l >> 4, qd = seg * 8;
  // q2 A-frag: A[m = slot = l&15][k = d]; slots 8..15 are zero rows.
  sx8 qf[4];
#pragma unroll
  for (int ks = 0; ks < 4; ks++) {
    if (nr < 8) {
      qf[ks] = *(const sx8*)(q2b + ((long)b * 8 + nr) * 128 + ks * 32 + qd);
    } else {
      sx8 t;
#pragma unroll
      for (int j = 0; j < 8; j++) t[j] = 0;
      qf[ks] = t;
    }
  }
  const fx4 z4 = {0.f, 0.f, 0.f, 0.f};
  float satacc[4] = {0.f, 0.f, 0.f, 0.f};
  short* ph = &plds[w * WREG];
  short* pl = ph + 16 * PSTR;
  // logits^T + per-lane softmax: lane holds s = seg*4+rg for row nr of this mt tile
#pragma unroll
  for (int mt = 0; mt < 4; mt++) {
    fx4 cc = z4;
#pragma unroll
    for (int ks = 0; ks < 4; ks++) {
      sx8 bfr = *(const sx8*)(xt + (mt * 16 + nr) * 128 + ks * 32 + qd);
      cc = MFMA(qf[ks], bfr, cc);
    }
    float m01 = fmaxf(fmaxf(cc[0], cc[1]), fmaxf(cc[2], cc[3]));
    m01 = fmaxf(m01, __shfl_xor(m01, 16, 64));
    float p0 = __expf(cc[0] - m01), p1 = __expf(cc[1] - m01),
          p2 = __expf(cc[2] - m01), p3 = __expf(cc[3] - m01);
    float sl = p0 + p1 + p2 + p3;
    sl += __shfl_xor(sl, 16, 64);
    float inv = 1.f / sl;
    float at0 = p0 * inv + 1e-8f, at1 = p1 * inv + 1e-8f;
    float at2 = p2 * inv + 1e-8f, at3 = p3 * inv + 1e-8f;
    satacc[0] += at0; satacc[1] += at1; satacc[2] += at2; satacc[3] += at3;
    int pb = mt * 16 + nr;
    unsigned short h0 = f2bf(at0), h1 = f2bf(at1), h2 = f2bf(at2), h3 = f2bf(at3);
    ph[(seg * 4 + 0) * PSTR + pb] = (short)h0;
    ph[(seg * 4 + 1) * PSTR + pb] = (short)h1;
    ph[(seg * 4 + 2) * PSTR + pb] = (short)h2;
    ph[(seg * 4 + 3) * PSTR + pb] = (short)h3;
    pl[(seg * 4 + 0) * PSTR + pb] = (short)f2bf(at0 - bf2f(h0));
    pl[(seg * 4 + 1) * PSTR + pb] = (short)f2bf(at1 - bf2f(h1));
    pl[(seg * 4 + 2) * PSTR + pb] = (short)f2bf(at2 - bf2f(h2));
    pl[(seg * 4 + 3) * PSTR + pb] = (short)f2bf(at3 - bf2f(h3));
  }
  // PV via MFMA: raw[s][d] = sum_n P^T[s][n] * xn[n][d]
  fx4 acc[8];
#pragma unroll
  for (int nt = 0; nt < 8; nt++) acc[nt] = z4;
#pragma unroll
  for (int ks2 = 0; ks2 < 2; ks2++) {
    sx8 pah = *(const sx8*)&ph[nr * PSTR + ks2 * 32 + seg * 8];
    sx8 pal = *(const sx8*)&pl[nr * PSTR + ks2 * 32 + seg * 8];
#pragma unroll
    for (int nt = 0; nt < 8; nt++) {
      const unsigned short* cp = xt + (ks2 * 32 + seg * 8) * 128 + nt * 16 + nr;
      sx8 bfr;
#pragma unroll
      for (int j = 0; j < 8; j++) bfr[j] = (short)cp[j * 128];
      acc[nt] = MFMA(pah, bfr, acc[nt]);
      acc[nt] = MFMA(pal, bfr, acc[nt]);
    }
  }
  // overlay: wave w's raw partial (8x128 fp32) reuses its own plds region
  // (all of this wave's P^T reads completed above; cross-wave after barrier)
  float* aw = (float*)ph;
  if (seg < 2) {
#pragma unroll
    for (int nt = 0; nt < 8; nt++)
#pragma unroll
      for (int rg = 0; rg < 4; rg++)
        aw[(seg * 4 + rg) * 128 + nt * 16 + nr] = acc[nt][rg];
  }
  // sat column sums: reduce across the 16-lane row group
#pragma unroll
  for (int rg = 0; rg < 4; rg++) {
    float v = satacc[rg];
    v += __shfl_xor(v, 1, 64);
    v += __shfl_xor(v, 2, 64);
    v += __shfl_xor(v, 4, 64);
    v += __shfl_xor(v, 8, 64);
    if (nr == 0 && seg < 2) sattnbuf[w * 8 + seg * 4 + rg] = v;
  }
  __syncthreads();
  {
    int i = tid * 4;
    const float* r0 = (const float*)&plds[0];
    const float* r1 = (const float*)&plds[WREG];
    const float* r2 = (const float*)&plds[2 * WREG];
    const float* r3 = (const float*)&plds[3 * WREG];
    fx4 o = *(const fx4*)&r0[i] + *(const fx4*)&r1[i] +
            *(const fx4*)&r2[i] + *(const fx4*)&r3[i];
    *(fx4*)(upd_part + ((size_t)(b * 16 + c)) * 1024 + i) = o;
    if (tid < 8)
      sattn_part[(b * 16 + c) * 8 + tid] =
          sattnbuf[tid] + sattnbuf[8 + tid] + sattnbuf[16 + tid] + sattnbuf[24 + tid];
  }
}

// ---------------- iter-0 attention with fused LN(x), transposed logits, MFMA PV ----
__global__ __launch_bounds__(256, 6) void k_attn_first(
    const float* __restrict__ x, unsigned short* __restrict__ ln16,
    const unsigned short* __restrict__ q2b,
    float* __restrict__ upd_part, float* __restrict__ sattn_part) {
  __shared__ __align__(16) short plds[4 * WREG];
  __shared__ float sattnbuf[4 * 8];
  int tid = threadIdx.x, w = tid >> 6, l = tid & 63;
  int b = blockIdx.x >> 4, c = blockIdx.x & 15;
  long base = (long)b * 4096 + (c * 4 + w) * 64;
  const float* xs = x + base * 128;
  unsigned short* xt = ln16 + base * 128;
  int nr = l & 15, seg = l >> 4, qd = seg * 8;
  sx8 qf[4];
#pragma unroll
  for (int ks = 0; ks < 4; ks++) {
    if (nr < 8) {
      qf[ks] = *(const sx8*)(q2b + ((long)b * 8 + nr) * 128 + ks * 32 + qd);
    } else {
      sx8 t;
#pragma unroll
      for (int j = 0; j < 8; j++) t[j] = 0;
      qf[ks] = t;
    }
  }
  const fx4 z4 = {0.f, 0.f, 0.f, 0.f};
  float satacc[4] = {0.f, 0.f, 0.f, 0.f};
  short* ph = &plds[w * WREG];
  short* pl = ph + 16 * PSTR;
  // per-mt: LN the 16 rows (lane owns one row-quarter), write bf16, logits^T, softmax
#pragma unroll
  for (int mt = 0; mt < 4; mt++) {
    const float* rp = xs + (mt * 16 + nr) * 128 + qd;
    float v[32];
    float sm = 0.f, s2 = 0.f;
#pragma unroll
    for (int ks = 0; ks < 4; ks++) {
      fx4 t0 = ntload4(rp + ks * 32);
      fx4 t1 = ntload4(rp + ks * 32 + 4);
      v[ks * 8 + 0] = t0.x; v[ks * 8 + 1] = t0.y; v[ks * 8 + 2] = t0.z; v[ks * 8 + 3] = t0.w;
      v[ks * 8 + 4] = t1.x; v[ks * 8 + 5] = t1.y; v[ks * 8 + 6] = t1.z; v[ks * 8 + 7] = t1.w;
      sm += t0.x + t0.y + t0.z + t0.w + t1.x + t1.y + t1.z + t1.w;
      s2 += t0.x * t0.x + t0.y * t0.y + t0.z * t0.z + t0.w * t0.w +
            t1.x * t1.x + t1.y * t1.y + t1.z * t1.z + t1.w * t1.w;
    }
    sm += __shfl_xor(sm, 16, 64);  sm += __shfl_xor(sm, 32, 64);
    s2 += __shfl_xor(s2, 16, 64);  s2 += __shfl_xor(s2, 32, 64);
    float mean = sm * 0.0078125f;
    float rstd = rsqrtf(s2 * 0.0078125f - mean * mean + 1e-5f);
    fx4 cc = z4;
#pragma unroll
    for (int ks = 0; ks < 4; ks++) {
      sx8 t;
#pragma unroll
      for (int j = 0; j < 8; j++) t[j] = (short)f2bf((v[ks * 8 + j] - mean) * rstd);
      *(sx8*)(xt + (mt * 16 + nr) * 128 + ks * 32 + qd) = t;
      cc = MFMA(qf[ks], t, cc);
    }
    float m01 = fmaxf(fmaxf(cc[0], cc[1]), fmaxf(cc[2], cc[3]));
    m01 = fmaxf(m01, __shfl_xor(m01, 16, 64));
    float p0 = __expf(cc[0] - m01), p1 = __expf(cc[1] - m01),
          p2 = __expf(cc[2] - m01), p3 = __expf(cc[3] - m01);
    float sl = p0 + p1 + p2 + p3;
    sl += __shfl_xor(sl, 16, 64);
    float inv = 1.f / sl;
    float at0 = p0 * inv + 1e-8f, at1 = p1 * inv + 1e-8f;
    float at2 = p2 * inv + 1e-8f, at3 = p3 * inv + 1e-8f;
    satacc[0] += at0; satacc[1] += at1; satacc[2] += at2; satacc[3] += at3;
    int pb = mt * 16 + nr;
    unsigned short h0 = f2bf(at0), h1 = f2bf(at1), h2 = f2bf(at2), h3 = f2bf(at3);
    ph[(seg * 4 + 0) * PSTR + pb] = (short)h0;
    ph[(seg * 4 + 1) * PSTR + pb] = (short)h1;
    ph[(seg * 4 + 2) * PSTR + pb] = (short)h2;
    ph[(seg * 4 + 3) * PSTR + pb] = (short)h3;
    pl[(seg * 4 + 0) * PSTR + pb] = (short)f2bf(at0 - bf2f(h0));
    pl[(seg * 4 + 1) * PSTR + pb] = (short)f2bf(at1 - bf2f(h1));
    pl[(seg * 4 + 2) * PSTR + pb] = (short)f2bf(at2 - bf2f(h2));
    pl[(seg * 4 + 3) * PSTR + pb] = (short)f2bf(at3 - bf2f(h3));
  }
  // wave's ln16 writes must be visible to its own column re-reads below
  __threadfence_block();
  fx4 acc[8];
#pragma unroll
  for (int nt = 0; nt < 8; nt++) acc[nt] = z4;
#pragma unroll
  for (int ks2 = 0; ks2 < 2; ks2++) {
    sx8 pah = *(const sx8*)&ph[nr * PSTR + ks2 * 32 + seg * 8];
    sx8 pal = *(const sx8*)&pl[nr * PSTR + ks2 * 32 + seg * 8];
#pragma unroll
    for (int nt = 0; nt < 8; nt++) {
      const unsigned short* cp = xt + (ks2 * 32 + seg * 8) * 128 + nt * 16 + nr;
      sx8 bfr;
#pragma unroll
      for (int j = 0; j < 8; j++) bfr[j] = (short)cp[j * 128];
      acc[nt] = MFMA(pah, bfr, acc[nt]);
      acc[nt] = MFMA(pal, bfr, acc[nt]);
    }
  }
  float* aw = (float*)ph;
  if (seg < 2) {
#pragma unroll
    for (int nt = 0; nt < 8; nt++)
#pragma unroll
      for (int rg = 0; rg < 4; rg++)
        aw[(seg * 4 + rg) * 128 + nt * 16 + nr] = acc[nt][rg];
  }
#pragma unroll
  for (int rg = 0; rg < 4; rg++) {
    float v = satacc[rg];
    v += __shfl_xor(v, 1, 64);
    v += __shfl_xor(v, 2, 64);
    v += __shfl_xor(v, 4, 64);
    v += __shfl_xor(v, 8, 64);
    if (nr == 0 && seg < 2) sattnbuf[w * 8 + seg * 4 + rg] = v;
  }
  __syncthreads();
  {
    int i = tid * 4;
    const float* r0 = (const float*)&plds[0];
    const float* r1 = (const float*)&plds[WREG];
    const float* r2 = (const float*)&plds[2 * WREG];
    const float* r3 = (const float*)&plds[3 * WREG];
    fx4 o = *(const fx4*)&r0[i] + *(const fx4*)&r1[i] +
            *(const fx4*)&r2[i] + *(const fx4*)&r3[i];
    *(fx4*)(upd_part + ((size_t)(b * 16 + c)) * 1024 + i) = o;
    if (tid < 8)
      sattn_part[(b * 16 + c) * 8 + tid] =
          sattnbuf[tid] + sattnbuf[8 + tid] + sattnbuf[16 + tid] + sattnbuf[24 + tid];
  }
}

// ---------------- GRU + MLP (+ fused next-iter LN+q2) ----------------
// 64 blocks x 256 thr; 16 slot-rows (2 batches) per block.
__global__ __launch_bounds__(256) void k_slot_post(
    const float* __restrict__ upd_part, const float* __restrict__ sattn_part,
    float* __restrict__ slots_n,
    const unsigned short* __restrict__ wihv_b, const unsigned short* __restrict__ whh_b,
    const float* __restrict__ b_ih, const float* __restrict__ b_hh,
    const unsigned short* __restrict__ w1_b, const float* __restrict__ b1,
    const unsigned short* __restrict__ w2_b, const float* __restrict__ b2,
    const unsigned short* __restrict__ wqk_b,
    unsigned short* __restrict__ q2_b, float* __restrict__ out_final, int final_flag) {
  __shared__ __align__(16) char smem[78336];
  float* gx = (float*)smem;                  // 24576 (16x384)
  float* gh = (float*)(smem + 24576);        // 24576
  float* xred = gx;                          // phase A overlay: 4*2048 floats
  short* xfr = (short*)(smem + 49152);       // 4096
  short* hfr = (short*)(smem + 53248);       // 4096
  short* ynf = (short*)(smem + 57344);       // 4096
  short* y1f = (short*)(smem + 61440);       // 8192
  float* snew = (float*)(smem + 69632);      // 16*132*4 = 8448
  float* satred = (float*)(smem + 78080);    // 256
  int tid = threadIdx.x, w = tid >> 6, l = tid & 63;
  int rowbase = blockIdx.x * 16;
  int r = l & 15, seg = l >> 4;
  {  // phase A: every wave reduces 4 chunks of raw partials
    int row = rowbase + r;
    int bb = row >> 3, ss = row & 7;
    float a[32];
#pragma unroll
    for (int i = 0; i < 32; i++) a[i] = 0.f;
    float satsum = 0.f;
#pragma unroll
    for (int ci = 0; ci < 4; ci++) {
      int ch = bb * 16 + w * 4 + ci;
      const float* up = upd_part + (size_t)ch * 1024 + ss * 128 + seg * 32;
#pragma unroll
      for (int i = 0; i < 8; i++) {
        fx4 t = *(const fx4*)(up + i * 4);
        a[i * 4 + 0] += t.x; a[i * 4 + 1] += t.y; a[i * 4 + 2] += t.z; a[i * 4 + 3] += t.w;
      }
      satsum += sattn_part[ch * 8 + ss];
    }
#pragma unroll
    for (int i = 0; i < 8; i++) {
      fx4 t = {a[i * 4], a[i * 4 + 1], a[i * 4 + 2], a[i * 4 + 3]};
      *(fx4*)&xred[w * 2048 + r * 128 + seg * 32 + i * 4] = t;
    }
    if (seg == 0) satred[w * 16 + r] = satsum;
  }
  __syncthreads();
  if (w == 0) {  // combine -> raw_scaled A-frags
    float inv = 1.f / (satred[r] + satred[16 + r] + satred[32 + r] + satred[48 + r]);
    float a[32];
#pragma unroll
    for (int i = 0; i < 8; i++) {
      fx4 t = *(const fx4*)&xred[r * 128 + seg * 32 + i * 4];
      fx4 t1 = *(const fx4*)&xred[2048 + r * 128 + seg * 32 + i * 4];
      fx4 t2 = *(const fx4*)&xred[4096 + r * 128 + seg * 32 + i * 4];
      fx4 t3 = *(const fx4*)&xred[6144 + r * 128 + seg * 32 + i * 4];
      t = t + t1 + t2 + t3;
      a[i * 4 + 0] = t.x * inv; a[i * 4 + 1] = t.y * inv;
      a[i * 4 + 2] = t.z * inv; a[i * 4 + 3] = t.w * inv;
    }
#pragma unroll
    for (int q = 0; q < 4; q++) {
      sx8 t;
#pragma unroll
      for (int j = 0; j < 8; j++) t[j] = (short)f2bf(a[q * 8 + j]);
      *(sx8*)&xfr[(seg * 64 + (r + 16 * q)) * 8] = t;
    }
  } else if (w == 1) {  // h = slots_n -> A-frags
    const float* hp = slots_n + (long)(rowbase + r) * 128 + seg * 32;
#pragma unroll
    for (int q = 0; q < 4; q++) {
      fx4 t0 = *(const fx4*)(hp + q * 8);
      fx4 t1 = *(const fx4*)(hp + q * 8 + 4);
      sx8 t;
      t[0] = (short)f2bf(t0.x); t[1] = (short)f2bf(t0.y);
      t[2] = (short)f2bf(t0.z); t[3] = (short)f2bf(t0.w);
      t[4] = (short)f2bf(t1.x); t[5] = (short)f2bf(t1.y);
      t[6] = (short)f2bf(t1.z); t[7] = (short)f2bf(t1.w);
      *(sx8*)&hfr[(seg * 64 + (r + 16 * q)) * 8] = t;
    }
  }
  __syncthreads();
  const fx4 z4 = {0.f, 0.f, 0.f, 0.f};
  {  // GEMM1: gx = raw_scaled@Wihv^T, gh = h@Whh^T
    fx4 ax[6], ah[6];
#pragma unroll
    for (int j = 0; j < 6; j++) { ax[j] = z4; ah[j] = z4; }
#pragma unroll
    for (int ks = 0; ks < 4; ks++) {
      sx8 a_x = *(const sx8*)&xfr[(ks * 64 + l) * 8];
      sx8 a_h = *(const sx8*)&hfr[(ks * 64 + l) * 8];
#pragma unroll
      for (int j = 0; j < 6; j++) {
        int nt = w * 6 + j;
        sx8 bx = *(const sx8*)(wihv_b + (nt * 16 + (l & 15)) * 128 + ks * 32 + (l >> 4) * 8);
        sx8 bh = *(const sx8*)(whh_b + (nt * 16 + (l & 15)) * 128 + ks * 32 + (l >> 4) * 8);
        ax[j] = MFMA(a_x, bx, ax[j]);
        ah[j] = MFMA(a_h, bh, ah[j]);
      }
    }
#pragma unroll
    for (int j = 0; j < 6; j++) {
      int col = (w * 6 + j) * 16 + (l & 15);
#pragma unroll
      for (int rg = 0; rg < 4; rg++) {
        int row = (l >> 4) * 4 + rg;
        gx[row * 384 + col] = ax[j][rg];
        gh[row * 384 + col] = ah[j][rg];
      }
    }
  }
  __syncthreads();
  {  // GRU gates
    int row = tid >> 4, j0 = (tid & 15) * 8;
#pragma unroll
    for (int j = j0; j < j0 + 8; j++) {
      float xr = gx[row * 384 + j] + b_ih[j];
      float xz = gx[row * 384 + 128 + j] + b_ih[128 + j];
      float xn = gx[row * 384 + 256 + j] + b_ih[256 + j];
      float hr = gh[row * 384 + j] + b_hh[j];
      float hz = gh[row * 384 + 128 + j] + b_hh[128 + j];
      float hn = gh[row * 384 + 256 + j] + b_hh[256 + j];
      float rr = 1.f / (1.f + __expf(-(xr + hr)));
      float zz = 1.f / (1.f + __expf(-(xz + hz)));
      float nn = tanhf(xn + rr * hn);
      float h = slots_n[(long)(rowbase + row) * 128 + j];
      snew[row * 132 + j] = (1.f - zz) * nn + zz * h;
    }
  }
  __syncthreads();
  if (w == 0) {  // LN(snew) -> ynf A-frags
    float v[32];
    float s = 0.f, s2 = 0.f;
#pragma unroll
    for (int i = 0; i < 32; i++) {
      float t = snew[r * 132 + seg * 32 + i];
      v[i] = t; s += t; s2 += t * t;
    }
    s += __shfl_xor(s, 16, 64);  s += __shfl_xor(s, 32, 64);
    s2 += __shfl_xor(s2, 16, 64); s2 += __shfl_xor(s2, 32, 64);
    float mean = s * 0.0078125f;
    float var = s2 * 0.0078125f - mean * mean;
    float rstd = rsqrtf(var + 1e-5f);
#pragma unroll
    for (int q = 0; q < 4; q++) {
      sx8 t;
#pragma unroll
      for (int j = 0; j < 8; j++) t[j] = (short)f2bf((v[q * 8 + j] - mean) * rstd);
      *(sx8*)&ynf[(seg * 64 + (r + 16 * q)) * 8] = t;
    }
  }
  __syncthreads();
  {  // GEMM2: y1 = relu(LN@W1^T + b1) -> A-frags for GEMM3
    fx4 y[4];
#pragma unroll
    for (int j = 0; j < 4; j++) y[j] = z4;
#pragma unroll
    for (int ks = 0; ks < 4; ks++) {
      sx8 a = *(const sx8*)&ynf[(ks * 64 + l) * 8];
#pragma unroll
      for (int j = 0; j < 4; j++) {
        int nt = w * 4 + j;
        sx8 bf = *(const sx8*)(w1_b + (nt * 16 + (l & 15)) * 128 + ks * 32 + (l >> 4) * 8);
        y[j] = MFMA(a, bf, y[j]);
      }
    }
#pragma unroll
    for (int j = 0; j < 4; j++) {
      int col = (w * 4 + j) * 16 + (l & 15);
      float bias = b1[col];
      int ks3 = col >> 5, qq = (col >> 3) & 3, jj = col & 7;
#pragma unroll
      for (int rg = 0; rg < 4; rg++) {
        float val = fmaxf(y[j][rg] + bias, 0.f);
        int m = (l >> 4) * 4 + rg;
        y1f[(ks3 * 64 + m + 16 * qq) * 8 + jj] = (short)f2bf(val);
      }
    }
  }
  __syncthreads();
  {  // GEMM3: snew += y1@W2^T + b2
    fx4 zz2[2];
    zz2[0] = z4; zz2[1] = z4;
#pragma unroll
    for (int ks = 0; ks < 8; ks++) {
      sx8 a = *(const sx8*)&y1f[(ks * 64 + l) * 8];
#pragma unroll
      for (int j = 0; j < 2; j++) {
        sx8 bf = *(const sx8*)(w2_b + ((w * 2 + j) * 16 + (l & 15)) * 256 + ks * 32 + (l >> 4) * 8);
        zz2[j] = MFMA(a, bf, zz2[j]);
      }
    }
#pragma unroll
    for (int j = 0; j < 2; j++) {
      int col = (w * 2 + j) * 16 + (l & 15);
      float bias = b2[col];
#pragma unroll
      for (int rg = 0; rg < 4; rg++) {
        int row = (l >> 4) * 4 + rg;
        snew[row * 132 + col] += zz2[j][rg] + bias;
      }
    }
  }
  __syncthreads();
  if (final_flag) {
    int row = tid >> 4, c8 = (tid & 15) * 8;
    fx4 t0 = *(const fx4*)&snew[row * 132 + c8];
    fx4 t1 = *(const fx4*)&snew[row * 132 + c8 + 4];
    *(fx4*)(out_final + (long)(rowbase + row) * 128 + c8) = t0;
    *(fx4*)(out_final + (long)(rowbase + row) * 128 + c8 + 4) = t1;
    return;
  }
  // fused next-iter: LN(new slots) -> slots_n + q2
  if (w == 0) {
    float v[32];
    float s = 0.f, s2 = 0.f;
#pragma unroll
    for (int i = 0; i < 32; i++) {
      float t = snew[r * 132 + seg * 32 + i];
      v[i] = t; s += t; s2 += t * t;
    }
    s += __shfl_xor(s, 16, 64);  s += __shfl_xor(s, 32, 64);
    s2 += __shfl_xor(s2, 16, 64); s2 += __shfl_xor(s2, 32, 64);
    float mean = s * 0.0078125f;
    float var = s2 * 0.0078125f - mean * mean;
    float rstd = rsqrtf(var + 1e-5f);
    float* snp = slots_n + (long)(rowbase + r) * 128 + seg * 32;
#pragma unroll
    for (int i = 0; i < 8; i++) {
      fx4 t = {(v[i * 4 + 0] - mean) * rstd, (v[i * 4 + 1] - mean) * rstd,
               (v[i * 4 + 2] - mean) * rstd, (v[i * 4 + 3] - mean) * rstd};
      *(fx4*)(snp + i * 4) = t;
      v[i * 4 + 0] = t.x; v[i * 4 + 1] = t.y; v[i * 4 + 2] = t.z; v[i * 4 + 3] = t.w;
    }
#pragma unroll
    for (int q = 0; q < 4; q++) {
      sx8 t;
#pragma unroll
      for (int j = 0; j < 8; j++) t[j] = (short)f2bf(v[q * 8 + j]);
      *(sx8*)&ynf[(seg * 64 + (r + 16 * q)) * 8] = t;
    }
  }
  __syncthreads();
  {  // q2 GEMM: wave w computes nt = w*2, w*2+1
    fx4 acc2[2];
    acc2[0] = z4; acc2[1] = z4;
#pragma unroll
    for (int ks = 0; ks < 4; ks++) {
      sx8 a = *(const sx8*)&ynf[(ks * 64 + l) * 8];
#pragma unroll
      for (int j = 0; j < 2; j++) {
        int nt = w * 2 + j;
        sx8 bf = *(const sx8*)(wqk_b + (nt * 16 + (l & 15)) * 128 + ks * 32 + (l >> 4) * 8);
        acc2[j] = MFMA(a, bf, acc2[j]);
      }
    }
    int cl = l & 15, rq = (l >> 4) * 4;
#pragma unroll
    for (int j = 0; j < 2; j++) {
      int nt = w * 2 + j;
#pragma unroll
      for (int rg = 0; rg < 4; rg++)
        q2_b[(long)(rowbase + rq + rg) * 128 + nt * 16 + cl] = f2bf(acc2[j][rg]);
    }
  }
}

extern "C" void kernel_launch(void* const* d_in, const int* in_sizes, int n_in,
                              void* d_out, int out_size, void* d_ws, size_t ws_size,
                              hipStream_t stream) {
  (void)in_sizes; (void)n_in; (void)out_size; (void)ws_size;
  const float* x = (const float*)d_in[0];
  const float* noise = (const float*)d_in[1];
  const float* mu = (const float*)d_in[2];
  const float* lsig = (const float*)d_in[3];
  const float* Wq = (const float*)d_in[4];
  const float* Wk = (const float*)d_in[5];
  const float* Wv = (const float*)d_in[6];
  const float* Wih = (const float*)d_in[7];
  const float* Whh = (const float*)d_in[8];
  const float* b_ih = (const float*)d_in[9];
  const float* b_hh = (const float*)d_in[10];
  const float* W1 = (const float*)d_in[11];
  const float* b1 = (const float*)d_in[12];
  const float* W2 = (const float*)d_in[13];
  const float* b2 = (const float*)d_in[14];

  char* ws = (char*)d_ws;
  size_t off = 0;
  auto take = [&](size_t bytes) {
    char* p = ws + off;
    off += (bytes + 255) & ~(size_t)255;
    return p;
  };
  unsigned short* ln16 = (unsigned short*)take(134217728);  // LN(x) bf16 row-major
  float* Wqk = (float*)take(65536);
  float* Wihv = (float*)take(196608);
  unsigned short* wqk_b = (unsigned short*)take(32768);
  unsigned short* wihv_b = (unsigned short*)take(98304);
  unsigned short* whh_b = (unsigned short*)take(98304);
  unsigned short* w1_b = (unsigned short*)take(65536);
  unsigned short* w2_b = (unsigned short*)take(65536);
  float* slots = (float*)take(524288);
  float* slots_n = (float*)take(524288);
  unsigned short* q2_b = (unsigned short*)take(262144);
  float* upd_part = (float*)take(8388608);    // raw partials (B,16,8,128) fp32
  float* sattn_part = (float*)take(65536);

  k_fold<<<256, 256, 0, stream>>>(Wq, Wk, Wih, Wv, Wqk, Wihv);
  k_pack<<<1216, 256, 0, stream>>>(noise, mu, lsig, Wqk, Wihv, Whh, W1, W2,
                                   slots, wqk_b, wihv_b, whh_b, w1_b, w2_b);
  k_slot_pre<<<64, 64, 0, stream>>>(slots, wqk_b, slots_n, q2_b);
  // iter 0: LN fused into the attention pass (no separate k_ln)
  k_attn_first<<<2048, 256, 0, stream>>>(x, ln16, q2_b, upd_part, sattn_part);
  k_slot_post<<<64, 256, 0, stream>>>(upd_part, sattn_part, slots_n, wihv_b, whh_b,
                                      b_ih, b_hh, w1_b, b1, w2_b, b2, wqk_b,
                                      q2_b, (float*)d_out, 0);
  for (int it = 1; it < 3; it++) {
    k_attn<<<2048, 256, 0, stream>>>(ln16, q2_b, upd_part, sattn_part);
    k_slot_post<<<64, 256, 0, stream>>>(upd_part, sattn_part, slots_n, wihv_b, whh_b,
                                        b_ih, b_hh, w1_b, b1, w2_b, b2, wqk_b,
                                        q2_b, (float*)d_out, (it == 2) ? 1 : 0);
  }
}

// Round 7
// 593.455 us; speedup vs baseline: 2.9158x; 1.1939x over previous
//
#include <hip/hip_runtime.h>
#include <math.h>

// B=128, N=4096, Din=128, D=128, S(slots)=8, H=256, 3 iterations.
// Algebraic folds: logits = xn @ q2^T with q2 = slots_n @ Wqk, Wqk = scale*Wq^T@Wk.
// gx = raw @ Wihv^T with raw = attn^T @ xn (per-chunk partials), Wihv = Wih@Wv.
// R0: LN(x) fused into iter-0 attention. R2: MFMA PV with P hi/lo bf16 split.
// R3: transposed logits + per-lane softmax. R4 (reverted): tail-block fusion.
// R6: PV B-frags no longer 2-byte column gathers from GLOBAL ln16 (R5 counters:
//   376MB FETCH / 250MB WRITE on k_attn_first = L2 thrash from the transpose
//   gather). Blocks now cover 64 rows; each wave LNs/loads its 16 rows once
//   (coalesced), keeps them in regs for logits, and stages them in a shared
//   16KB LDS X-tile (XOR swizzle ((n>>3)&3)<<5 -> conflict-free PV reads).
//   PV reads B-frags from LDS. Each ln16/x element fetched exactly once/iter.
// MFMA 16x16x32 bf16 layouts (verified):
//   C/D: col = lane&15, row = (lane>>4)*4 + reg
//   A  : A[m = lane&15][k = (lane>>4)*8 + j]
//   B  : B[k = (lane>>4)*8 + j][n = lane&15]  (row-major [N][K] source)

typedef __attribute__((ext_vector_type(4))) float fx4;
typedef __attribute__((ext_vector_type(8))) short sx8;
typedef __attribute__((ext_vector_type(8))) __bf16 bfx8;

static __device__ __forceinline__ fx4 MFMA(sx8 a, sx8 b, fx4 c) {
  return __builtin_amdgcn_mfma_f32_16x16x32_bf16(
      __builtin_bit_cast(bfx8, a), __builtin_bit_cast(bfx8, b), c, 0, 0, 0);
}

static __device__ __forceinline__ unsigned short f2bf(float f) {
  union { float f; unsigned u; } x; x.f = f;
  unsigned r = x.u + 0x7fffu + ((x.u >> 16) & 1u);  // RNE
  return (unsigned short)(r >> 16);
}
static __device__ __forceinline__ float bf2f(unsigned short u) {
  union { unsigned u; float f; } x; x.u = ((unsigned)u) << 16; return x.f;
}
static __device__ __forceinline__ fx4 ntload4(const float* p) {
  return __builtin_nontemporal_load((const fx4*)p);
}

#define PST 72  // P^T plane row stride (shorts); 144B rows, 16B-aligned frags

// ---------------- fold: Wqk = scale*Wq^T@Wk (fp32), Wihv = Wih@Wv (fp32) -------------
__global__ __launch_bounds__(256) void k_fold(
    const float* __restrict__ Wq, const float* __restrict__ Wk,
    const float* __restrict__ Wih, const float* __restrict__ Wv,
    float* __restrict__ Wqk, float* __restrict__ Wihv) {
  int idx = blockIdx.x * 256 + threadIdx.x;
  if (idx < 16384) {
    int e = idx >> 7, c = idx & 127;
    float s = 0.f;
#pragma unroll 4
    for (int d = 0; d < 128; d++) s += Wq[d * 128 + e] * Wk[d * 128 + c];
    Wqk[idx] = s * 0.08838834764831845f;
    return;
  }
  idx -= 16384;
  if (idx < 49152) {
    int g = idx >> 7, c = idx & 127;
    float s = 0.f;
#pragma unroll 4
    for (int d = 0; d < 128; d++) s += Wih[g * 128 + d] * Wv[d * 128 + c];
    Wihv[idx] = s;
  }
}

// ---------------- pack: slots init + bf16 weight tables ----------------
__global__ __launch_bounds__(256) void k_pack(
    const float* __restrict__ noise, const float* __restrict__ mu,
    const float* __restrict__ lsig, const float* __restrict__ Wqk,
    const float* __restrict__ Wihv, const float* __restrict__ Whh,
    const float* __restrict__ W1, const float* __restrict__ W2,
    float* __restrict__ slots, unsigned short* __restrict__ wqk_b,
    unsigned short* __restrict__ wihv_b, unsigned short* __restrict__ whh_b,
    unsigned short* __restrict__ w1_b, unsigned short* __restrict__ w2_b) {
  int idx = blockIdx.x * 256 + threadIdx.x;
  if (idx < 131072) {
    int d = idx & 127;
    slots[idx] = mu[d] + expf(lsig[d]) * noise[idx];
    return;
  }
  idx -= 131072;
  if (idx < 16384) {  // wqk_b row-major [n=c][k=e] <- Wqk[e,c]
    wqk_b[idx] = f2bf(Wqk[(idx & 127) * 128 + (idx >> 7)]);
    return;
  }
  idx -= 16384;
  if (idx < 49152) { wihv_b[idx] = f2bf(Wihv[idx]); return; }
  idx -= 49152;
  if (idx < 49152) { whh_b[idx] = f2bf(Whh[idx]); return; }
  idx -= 49152;
  if (idx < 32768) { w1_b[idx] = f2bf(W1[idx]); return; }
  idx -= 32768;
  w2_b[idx] = f2bf(W2[idx]);
}

// ---------------- iter0 only: LN(slots) + q2 = slots_n @ Wqk ----------------
__global__ __launch_bounds__(64) void k_slot_pre(
    const float* __restrict__ slots, const unsigned short* __restrict__ wqk_b,
    float* __restrict__ slots_n, unsigned short* __restrict__ q2_b) {
  __shared__ __align__(16) short xf[4 * 64 * 8];
  int l = threadIdx.x;
  int r = l & 15, seg = l >> 4;
  long rowbase = (long)blockIdx.x * 16;
  {
    const float* xp = slots + (rowbase + r) * 128 + seg * 32;
    float* snp = slots_n + (rowbase + r) * 128 + seg * 32;
    float v[32];
    float s = 0.f, s2 = 0.f;
#pragma unroll
    for (int i = 0; i < 8; i++) {
      fx4 t = *(const fx4*)(xp + i * 4);
      v[i * 4 + 0] = t.x; v[i * 4 + 1] = t.y; v[i * 4 + 2] = t.z; v[i * 4 + 3] = t.w;
      s += t.x + t.y + t.z + t.w;
      s2 += t.x * t.x + t.y * t.y + t.z * t.z + t.w * t.w;
    }
    s += __shfl_xor(s, 16, 64);  s += __shfl_xor(s, 32, 64);
    s2 += __shfl_xor(s2, 16, 64); s2 += __shfl_xor(s2, 32, 64);
    float mean = s * 0.0078125f;
    float var = s2 * 0.0078125f - mean * mean;
    float rstd = rsqrtf(var + 1e-5f);
#pragma unroll
    for (int i = 0; i < 8; i++) {
      fx4 t = {(v[i * 4 + 0] - mean) * rstd, (v[i * 4 + 1] - mean) * rstd,
               (v[i * 4 + 2] - mean) * rstd, (v[i * 4 + 3] - mean) * rstd};
      *(fx4*)(snp + i * 4) = t;
      v[i * 4 + 0] = t.x; v[i * 4 + 1] = t.y; v[i * 4 + 2] = t.z; v[i * 4 + 3] = t.w;
    }
#pragma unroll
    for (int q = 0; q < 4; q++) {
      sx8 t;
#pragma unroll
      for (int j = 0; j < 8; j++) t[j] = (short)f2bf(v[q * 8 + j]);
      *(sx8*)&xf[(seg * 64 + (r + 16 * q)) * 8] = t;
    }
  }
  __syncthreads();
  const fx4 z4 = {0.f, 0.f, 0.f, 0.f};
  fx4 acc[8];
#pragma unroll
  for (int nt = 0; nt < 8; nt++) acc[nt] = z4;
#pragma unroll
  for (int ks = 0; ks < 4; ks++) {
    sx8 a = *(const sx8*)&xf[(ks * 64 + l) * 8];
#pragma unroll
    for (int nt = 0; nt < 8; nt++) {
      sx8 bfr = *(const sx8*)(wqk_b + (nt * 16 + (l & 15)) * 128 + ks * 32 + (l >> 4) * 8);
      acc[nt] = MFMA(a, bfr, acc[nt]);
    }
  }
  int cl = l & 15, rq = (l >> 4) * 4;
#pragma unroll
  for (int nt = 0; nt < 8; nt++)
#pragma unroll
    for (int rg = 0; rg < 4; rg++)
      q2_b[(rowbase + rq + rg) * 128 + nt * 16 + cl] = f2bf(acc[nt][rg]);
}

// ---------------- attention (iters 1-2): 64-row blocks, LDS X-tile ----------------
// grid = 128 b * 64 chunks = 8192 blocks, 256 thr. Wave w owns rows w*16..+16 for
// load/logits; PV shares the block X-tile, wave w computes d-tiles 2w, 2w+1.
__global__ __launch_bounds__(256, 6) void k_attn(
    const unsigned short* __restrict__ ln16, const unsigned short* __restrict__ q2b,
    float* __restrict__ upd_part, float* __restrict__ sattn_part) {
  __shared__ __align__(16) short xlds[64 * 128];      // 16 KB, swizzled
  __shared__ __align__(16) short pplane[2][16 * PST]; // P^T hi/lo
  __shared__ float sattnbuf[32];
  int tid = threadIdx.x, w = tid >> 6, l = tid & 63;
  int b = blockIdx.x >> 6, c = blockIdx.x & 63;
  int nr = l & 15, seg = l >> 4, qd = seg * 8;
  int nloc = w * 16 + nr;
  const unsigned short* xt = ln16 + ((long)b * 4096 + c * 64 + nloc) * 128;
  sx8 qf[4];
#pragma unroll
  for (int ks = 0; ks < 4; ks++) {
    if (nr < 8) {
      qf[ks] = *(const sx8*)(q2b + ((long)b * 8 + nr) * 128 + ks * 32 + qd);
    } else {
      sx8 t;
#pragma unroll
      for (int j = 0; j < 8; j++) t[j] = 0;
      qf[ks] = t;
    }
  }
  const fx4 z4 = {0.f, 0.f, 0.f, 0.f};
  // load own row (coalesced 16B), stage to LDS (swizzled), logits MFMA from regs
  fx4 cc = z4;
  int qsw = ((nloc >> 3) & 3) << 5;
#pragma unroll
  for (int ks = 0; ks < 4; ks++) {
    sx8 xr = *(const sx8*)(xt + ks * 32 + qd);
    *(sx8*)&xlds[(nloc * 256 + ((ks * 64 + seg * 16) ^ qsw)) >> 1] = xr;
    cc = MFMA(qf[ks], xr, cc);
  }
  // per-lane softmax over the 8 slots (pairs via xor16)
  float m01 = fmaxf(fmaxf(cc[0], cc[1]), fmaxf(cc[2], cc[3]));
  m01 = fmaxf(m01, __shfl_xor(m01, 16, 64));
  float p0 = __expf(cc[0] - m01), p1 = __expf(cc[1] - m01),
        p2 = __expf(cc[2] - m01), p3 = __expf(cc[3] - m01);
  float sl = p0 + p1 + p2 + p3;
  sl += __shfl_xor(sl, 16, 64);
  float inv = 1.f / sl;
  float at0 = p0 * inv + 1e-8f, at1 = p1 * inv + 1e-8f;
  float at2 = p2 * inv + 1e-8f, at3 = p3 * inv + 1e-8f;
  {  // P^T hi/lo at [s][nloc]
    unsigned short h0 = f2bf(at0), h1 = f2bf(at1), h2 = f2bf(at2), h3 = f2bf(at3);
    pplane[0][(seg * 4 + 0) * PST + nloc] = (short)h0;
    pplane[0][(seg * 4 + 1) * PST + nloc] = (short)h1;
    pplane[0][(seg * 4 + 2) * PST + nloc] = (short)h2;
    pplane[0][(seg * 4 + 3) * PST + nloc] = (short)h3;
    pplane[1][(seg * 4 + 0) * PST + nloc] = (short)f2bf(at0 - bf2f(h0));
    pplane[1][(seg * 4 + 1) * PST + nloc] = (short)f2bf(at1 - bf2f(h1));
    pplane[1][(seg * 4 + 2) * PST + nloc] = (short)f2bf(at2 - bf2f(h2));
    pplane[1][(seg * 4 + 3) * PST + nloc] = (short)f2bf(at3 - bf2f(h3));
  }
  // sat column sums for this wave's 16 rows (reduce over nr lanes)
  {
    float v0 = at0, v1 = at1, v2 = at2, v3 = at3;
#pragma unroll
    for (int m = 1; m < 16; m <<= 1) {
      v0 += __shfl_xor(v0, m, 64); v1 += __shfl_xor(v1, m, 64);
      v2 += __shfl_xor(v2, m, 64); v3 += __shfl_xor(v3, m, 64);
    }
    if (nr == 0 && seg < 2) {
      sattnbuf[w * 8 + seg * 4 + 0] = v0;
      sattnbuf[w * 8 + seg * 4 + 1] = v1;
      sattnbuf[w * 8 + seg * 4 + 2] = v2;
      sattnbuf[w * 8 + seg * 4 + 3] = v3;
    }
  }
  __syncthreads();
  // PV: raw[s][d] = sum_n P^T[s][n]*X[n][d]; B-frags from swizzled LDS
  fx4 acc[2];
  acc[0] = z4; acc[1] = z4;
#pragma unroll
  for (int nt2 = 0; nt2 < 2; nt2++) {
    int cols = ((((w * 2 + nt2) * 16 + nr) * 2) ^ (seg << 5)) >> 1;
#pragma unroll
    for (int ks2 = 0; ks2 < 2; ks2++) {
      sx8 bfr;
#pragma unroll
      for (int j = 0; j < 8; j++)
        bfr[j] = xlds[(ks2 * 32 + seg * 8 + j) * 128 + cols];
      sx8 pah = *(const sx8*)&pplane[0][nr * PST + ks2 * 32 + seg * 8];
      sx8 pal = *(const sx8*)&pplane[1][nr * PST + ks2 * 32 + seg * 8];
      acc[nt2] = MFMA(pah, bfr, acc[nt2]);
      acc[nt2] = MFMA(pal, bfr, acc[nt2]);
    }
  }
  if (seg < 2) {  // valid s rows 0..7
    size_t ubase = (size_t)(b * 64 + c) * 1024;
#pragma unroll
    for (int nt2 = 0; nt2 < 2; nt2++)
#pragma unroll
      for (int rg = 0; rg < 4; rg++)
        upd_part[ubase + (seg * 4 + rg) * 128 + (w * 2 + nt2) * 16 + nr] = acc[nt2][rg];
  }
  if (tid < 8)
    sattn_part[(b * 64 + c) * 8 + tid] =
        sattnbuf[tid] + sattnbuf[8 + tid] + sattnbuf[16 + tid] + sattnbuf[24 + tid];
}

// ---------------- iter-0 attention: fused LN(x) + LDS X-tile ----------------
__global__ __launch_bounds__(256, 6) void k_attn_first(
    const float* __restrict__ x, unsigned short* __restrict__ ln16,
    const unsigned short* __restrict__ q2b,
    float* __restrict__ upd_part, float* __restrict__ sattn_part) {
  __shared__ __align__(16) short xlds[64 * 128];
  __shared__ __align__(16) short pplane[2][16 * PST];
  __shared__ float sattnbuf[32];
  int tid = threadIdx.x, w = tid >> 6, l = tid & 63;
  int b = blockIdx.x >> 6, c = blockIdx.x & 63;
  int nr = l & 15, seg = l >> 4, qd = seg * 8;
  int nloc = w * 16 + nr;
  long rowg = (long)b * 4096 + c * 64 + nloc;
  const float* xs = x + rowg * 128;
  unsigned short* xo = ln16 + rowg * 128;
  sx8 qf[4];
#pragma unroll
  for (int ks = 0; ks < 4; ks++) {
    if (nr < 8) {
      qf[ks] = *(const sx8*)(q2b + ((long)b * 8 + nr) * 128 + ks * 32 + qd);
    } else {
      sx8 t;
#pragma unroll
      for (int j = 0; j < 8; j++) t[j] = 0;
      qf[ks] = t;
    }
  }
  const fx4 z4 = {0.f, 0.f, 0.f, 0.f};
  // LN of own row: lane holds 32 of the 128 cols; reduce across 4 segs
  float v[32];
  float sm = 0.f, s2 = 0.f;
#pragma unroll
  for (int ks = 0; ks < 4; ks++) {
    fx4 t0 = ntload4(xs + ks * 32 + qd - qd + ks * 0 + ks * 32 + qd * 0 + qd);  // placeholder
    t0 = ntload4(xs + ks * 32 + qd);
    fx4 t1 = ntload4(xs + ks * 32 + qd + 4);
    v[ks * 8 + 0] = t0.x; v[ks * 8 + 1] = t0.y; v[ks * 8 + 2] = t0.z; v[ks * 8 + 3] = t0.w;
    v[ks * 8 + 4] = t1.x; v[ks * 8 + 5] = t1.y; v[ks * 8 + 6] = t1.z; v[ks * 8 + 7] = t1.w;
    sm += t0.x + t0.y + t0.z + t0.w + t1.x + t1.y + t1.z + t1.w;
    s2 += t0.x * t0.x + t0.y * t0.y + t0.z * t0.z + t0.w * t0.w +
          t1.x * t1.x + t1.y * t1.y + t1.z * t1.z + t1.w * t1.w;
  }
  sm += __shfl_xor(sm, 16, 64);  sm += __shfl_xor(sm, 32, 64);
  s2 += __shfl_xor(s2, 16, 64);  s2 += __shfl_xor(s2, 32, 64);
  float mean = sm * 0.0078125f;
  float rstd = rsqrtf(s2 * 0.0078125f - mean * mean + 1e-5f);
  fx4 cc = z4;
  int qsw = ((nloc >> 3) & 3) << 5;
#pragma unroll
  for (int ks = 0; ks < 4; ks++) {
    sx8 t;
#pragma unroll
    for (int j = 0; j < 8; j++) t[j] = (short)f2bf((v[ks * 8 + j] - mean) * rstd);
    *(sx8*)(xo + ks * 32 + qd) = t;
    *(sx8*)&xlds[(nloc * 256 + ((ks * 64 + seg * 16) ^ qsw)) >> 1] = t;
    cc = MFMA(qf[ks], t, cc);
  }
  float m01 = fmaxf(fmaxf(cc[0], cc[1]), fmaxf(cc[2], cc[3]));
  m01 = fmaxf(m01, __shfl_xor(m01, 16, 64));
  float p0 = __expf(cc[0] - m01), p1 = __expf(cc[1] - m01),
        p2 = __expf(cc[2] - m01), p3 = __expf(cc[3] - m01);
  float sl = p0 + p1 + p2 + p3;
  sl += __shfl_xor(sl, 16, 64);
  float inv = 1.f / sl;
  float at0 = p0 * inv + 1e-8f, at1 = p1 * inv + 1e-8f;
  float at2 = p2 * inv + 1e-8f, at3 = p3 * inv + 1e-8f;
  {
    unsigned short h0 = f2bf(at0), h1 = f2bf(at1), h2 = f2bf(at2), h3 = f2bf(at3);
    pplane[0][(seg * 4 + 0) * PST + nloc] = (short)h0;
    pplane[0][(seg * 4 + 1) * PST + nloc] = (short)h1;
    pplane[0][(seg * 4 + 2) * PST + nloc] = (short)h2;
    pplane[0][(seg * 4 + 3) * PST + nloc] = (short)h3;
    pplane[1][(seg * 4 + 0) * PST + nloc] = (short)f2bf(at0 - bf2f(h0));
    pplane[1][(seg * 4 + 1) * PST + nloc] = (short)f2bf(at1 - bf2f(h1));
    pplane[1][(seg * 4 + 2) * PST + nloc] = (short)f2bf(at2 - bf2f(h2));
    pplane[1][(seg * 4 + 3) * PST + nloc] = (short)f2bf(at3 - bf2f(h3));
  }
  {
    float v0 = at0, v1 = at1, v2 = at2, v3 = at3;
#pragma unroll
    for (int m = 1; m < 16; m <<= 1) {
      v0 += __shfl_xor(v0, m, 64); v1 += __shfl_xor(v1, m, 64);
      v2 += __shfl_xor(v2, m, 64); v3 += __shfl_xor(v3, m, 64);
    }
    if (nr == 0 && seg < 2) {
      sattnbuf[w * 8 + seg * 4 + 0] = v0;
      sattnbuf[w * 8 + seg * 4 + 1] = v1;
      sattnbuf[w * 8 + seg * 4 + 2] = v2;
      sattnbuf[w * 8 + seg * 4 + 3] = v3;
    }
  }
  __syncthreads();
  fx4 acc[2];
  acc[0] = z4; acc[1] = z4;
#pragma unroll
  for (int nt2 = 0; nt2 < 2; nt2++) {
    int cols = ((((w * 2 + nt2) * 16 + nr) * 2) ^ (seg << 5)) >> 1;
#pragma unroll
    for (int ks2 = 0; ks2 < 2; ks2++) {
      sx8 bfr;
#pragma unroll
      for (int j = 0; j < 8; j++)
        bfr[j] = xlds[(ks2 * 32 + seg * 8 + j) * 128 + cols];
      sx8 pah = *(const sx8*)&pplane[0][nr * PST + ks2 * 32 + seg * 8];
      sx8 pal = *(const sx8*)&pplane[1][nr * PST + ks2 * 32 + seg * 8];
      acc[nt2] = MFMA(pah, bfr, acc[nt2]);
      acc[nt2] = MFMA(pal, bfr, acc[nt2]);
    }
  }
  if (seg < 2) {
    size_t ubase = (size_t)(b * 64 + c) * 1024;
#pragma unroll
    for (int nt2 = 0; nt2 < 2; nt2++)
#pragma unroll
      for (int rg = 0; rg < 4; rg++)
        upd_part[ubase + (seg * 4 + rg) * 128 + (w * 2 + nt2) * 16 + nr] = acc[nt2][rg];
  }
  if (tid < 8)
    sattn_part[(b * 64 + c) * 8 + tid] =
        sattnbuf[tid] + sattnbuf[8 + tid] + sattnbuf[16 + tid] + sattnbuf[24 + tid];
}

// ---------------- GRU + MLP (+ fused next-iter LN+q2) ----------------
// 64 blocks x 256 thr; 16 slot-rows (2 batches) per block. 64 chunks/batch now.
__global__ __launch_bounds__(256) void k_slot_post(
    const float* __restrict__ upd_part, const float* __restrict__ sattn_part,
    float* __restrict__ slots_n,
    const unsigned short* __restrict__ wihv_b, const unsigned short* __restrict__ whh_b,
    const float* __restrict__ b_ih, const float* __restrict__ b_hh,
    const unsigned short* __restrict__ w1_b, const float* __restrict__ b1,
    const unsigned short* __restrict__ w2_b, const float* __restrict__ b2,
    const unsigned short* __restrict__ wqk_b,
    unsigned short* __restrict__ q2_b, float* __restrict__ out_final, int final_flag) {
  __shared__ __align__(16) char smem[78336];
  float* gx = (float*)smem;                  // 24576 (16x384)
  float* gh = (float*)(smem + 24576);        // 24576
  float* xred = gx;                          // phase A overlay: 4*2048 floats
  short* xfr = (short*)(smem + 49152);       // 4096
  short* hfr = (short*)(smem + 53248);       // 4096
  short* ynf = (short*)(smem + 57344);       // 4096
  short* y1f = (short*)(smem + 61440);       // 8192
  float* snew = (float*)(smem + 69632);      // 16*132*4 = 8448
  float* satred = (float*)(smem + 78080);    // 256
  int tid = threadIdx.x, w = tid >> 6, l = tid & 63;
  int rowbase = blockIdx.x * 16;
  int r = l & 15, seg = l >> 4;
  {  // phase A: every wave reduces 16 chunks of raw partials
    int row = rowbase + r;
    int bb = row >> 3, ss = row & 7;
    float a[32];
#pragma unroll
    for (int i = 0; i < 32; i++) a[i] = 0.f;
    float satsum = 0.f;
#pragma unroll 4
    for (int ci = 0; ci < 16; ci++) {
      int ch = bb * 64 + w * 16 + ci;
      const float* up = upd_part + (size_t)ch * 1024 + ss * 128 + seg * 32;
#pragma unroll
      for (int i = 0; i < 8; i++) {
        fx4 t = *(const fx4*)(up + i * 4);
        a[i * 4 + 0] += t.x; a[i * 4 + 1] += t.y; a[i * 4 + 2] += t.z; a[i * 4 + 3] += t.w;
      }
      satsum += sattn_part[ch * 8 + ss];
    }
#pragma unroll
    for (int i = 0; i < 8; i++) {
      fx4 t = {a[i * 4], a[i * 4 + 1], a[i * 4 + 2], a[i * 4 + 3]};
      *(fx4*)&xred[w * 2048 + r * 128 + seg * 32 + i * 4] = t;
    }
    if (seg == 0) satred[w * 16 + r] = satsum;
  }
  __syncthreads();
  if (w == 0) {  // combine -> raw_scaled A-frags
    float inv = 1.f / (satred[r] + satred[16 + r] + satred[32 + r] + satred[48 + r]);
    float a[32];
#pragma unroll
    for (int i = 0; i < 8; i++) {
      fx4 t = *(const fx4*)&xred[r * 128 + seg * 32 + i * 4];
      fx4 t1 = *(const fx4*)&xred[2048 + r * 128 + seg * 32 + i * 4];
      fx4 t2 = *(const fx4*)&xred[4096 + r * 128 + seg * 32 + i * 4];
      fx4 t3 = *(const fx4*)&xred[6144 + r * 128 + seg * 32 + i * 4];
      t = t + t1 + t2 + t3;
      a[i * 4 + 0] = t.x * inv; a[i * 4 + 1] = t.y * inv;
      a[i * 4 + 2] = t.z * inv; a[i * 4 + 3] = t.w * inv;
    }
#pragma unroll
    for (int q = 0; q < 4; q++) {
      sx8 t;
#pragma unroll
      for (int j = 0; j < 8; j++) t[j] = (short)f2bf(a[q * 8 + j]);
      *(sx8*)&xfr[(seg * 64 + (r + 16 * q)) * 8] = t;
    }
  } else if (w == 1) {  // h = slots_n -> A-frags
    const float* hp = slots_n + (long)(rowbase + r) * 128 + seg * 32;
#pragma unroll
    for (int q = 0; q < 4; q++) {
      fx4 t0 = *(const fx4*)(hp + q * 8);
      fx4 t1 = *(const fx4*)(hp + q * 8 + 4);
      sx8 t;
      t[0] = (short)f2bf(t0.x); t[1] = (short)f2bf(t0.y);
      t[2] = (short)f2bf(t0.z); t[3] = (short)f2bf(t0.w);
      t[4] = (short)f2bf(t1.x); t[5] = (short)f2bf(t1.y);
      t[6] = (short)f2bf(t1.z); t[7] = (short)f2bf(t1.w);
      *(sx8*)&hfr[(seg * 64 + (r + 16 * q)) * 8] = t;
    }
  }
  __syncthreads();
  const fx4 z4 = {0.f, 0.f, 0.f, 0.f};
  {  // GEMM1: gx = raw_scaled@Wihv^T, gh = h@Whh^T
    fx4 ax[6], ah[6];
#pragma unroll
    for (int j = 0; j < 6; j++) { ax[j] = z4; ah[j] = z4; }
#pragma unroll
    for (int ks = 0; ks < 4; ks++) {
      sx8 a_x = *(const sx8*)&xfr[(ks * 64 + l) * 8];
      sx8 a_h = *(const sx8*)&hfr[(ks * 64 + l) * 8];
#pragma unroll
      for (int j = 0; j < 6; j++) {
        int nt = w * 6 + j;
        sx8 bx = *(const sx8*)(wihv_b + (nt * 16 + (l & 15)) * 128 + ks * 32 + (l >> 4) * 8);
        sx8 bh = *(const sx8*)(whh_b + (nt * 16 + (l & 15)) * 128 + ks * 32 + (l >> 4) * 8);
        ax[j] = MFMA(a_x, bx, ax[j]);
        ah[j] = MFMA(a_h, bh, ah[j]);
      }
    }
#pragma unroll
    for (int j = 0; j < 6; j++) {
      int col = (w * 6 + j) * 16 + (l & 15);
#pragma unroll
      for (int rg = 0; rg < 4; rg++) {
        int row = (l >> 4) * 4 + rg;
        gx[row * 384 + col] = ax[j][rg];
        gh[row * 384 + col] = ah[j][rg];
      }
    }
  }
  __syncthreads();
  {  // GRU gates
    int row = tid >> 4, j0 = (tid & 15) * 8;
#pragma unroll
    for (int j = j0; j < j0 + 8; j++) {
      float xr = gx[row * 384 + j] + b_ih[j];
      float xz = gx[row * 384 + 128 + j] + b_ih[128 + j];
      float xn = gx[row * 384 + 256 + j] + b_ih[256 + j];
      float hr = gh[row * 384 + j] + b_hh[j];
      float hz = gh[row * 384 + 128 + j] + b_hh[128 + j];
      float hn = gh[row * 384 + 256 + j] + b_hh[256 + j];
      float rr = 1.f / (1.f + __expf(-(xr + hr)));
      float zz = 1.f / (1.f + __expf(-(xz + hz)));
      float nn = tanhf(xn + rr * hn);
      float h = slots_n[(long)(rowbase + row) * 128 + j];
      snew[row * 132 + j] = (1.f - zz) * nn + zz * h;
    }
  }
  __syncthreads();
  if (w == 0) {  // LN(snew) -> ynf A-frags
    float v[32];
    float s = 0.f, s2 = 0.f;
#pragma unroll
    for (int i = 0; i < 32; i++) {
      float t = snew[r * 132 + seg * 32 + i];
      v[i] = t; s += t; s2 += t * t;
    }
    s += __shfl_xor(s, 16, 64);  s += __shfl_xor(s, 32, 64);
    s2 += __shfl_xor(s2, 16, 64); s2 += __shfl_xor(s2, 32, 64);
    float mean = s * 0.0078125f;
    float var = s2 * 0.0078125f - mean * mean;
    float rstd = rsqrtf(var + 1e-5f);
#pragma unroll
    for (int q = 0; q < 4; q++) {
      sx8 t;
#pragma unroll
      for (int j = 0; j < 8; j++) t[j] = (short)f2bf((v[q * 8 + j] - mean) * rstd);
      *(sx8*)&ynf[(seg * 64 + (r + 16 * q)) * 8] = t;
    }
  }
  __syncthreads();
  {  // GEMM2: y1 = relu(LN@W1^T + b1) -> A-frags for GEMM3
    fx4 y[4];
#pragma unroll
    for (int j = 0; j < 4; j++) y[j] = z4;
#pragma unroll
    for (int ks = 0; ks < 4; ks++) {
      sx8 a = *(const sx8*)&ynf[(ks * 64 + l) * 8];
#pragma unroll
      for (int j = 0; j < 4; j++) {
        int nt = w * 4 + j;
        sx8 bf = *(const sx8*)(w1_b + (nt * 16 + (l & 15)) * 128 + ks * 32 + (l >> 4) * 8);
        y[j] = MFMA(a, bf, y[j]);
      }
    }
#pragma unroll
    for (int j = 0; j < 4; j++) {
      int col = (w * 4 + j) * 16 + (l & 15);
      float bias = b1[col];
      int ks3 = col >> 5, qq = (col >> 3) & 3, jj = col & 7;
#pragma unroll
      for (int rg = 0; rg < 4; rg++) {
        float val = fmaxf(y[j][rg] + bias, 0.f);
        int m = (l >> 4) * 4 + rg;
        y1f[(ks3 * 64 + m + 16 * qq) * 8 + jj] = (short)f2bf(val);
      }
    }
  }
  __syncthreads();
  {  // GEMM3: snew += y1@W2^T + b2
    fx4 zz2[2];
    zz2[0] = z4; zz2[1] = z4;
#pragma unroll
    for (int ks = 0; ks < 8; ks++) {
      sx8 a = *(const sx8*)&y1f[(ks * 64 + l) * 8];
#pragma unroll
      for (int j = 0; j < 2; j++) {
        sx8 bf = *(const sx8*)(w2_b + ((w * 2 + j) * 16 + (l & 15)) * 256 + ks * 32 + (l >> 4) * 8);
        zz2[j] = MFMA(a, bf, zz2[j]);
      }
    }
#pragma unroll
    for (int j = 0; j < 2; j++) {
      int col = (w * 2 + j) * 16 + (l & 15);
      float bias = b2[col];
#pragma unroll
      for (int rg = 0; rg < 4; rg++) {
        int row = (l >> 4) * 4 + rg;
        snew[row * 132 + col] += zz2[j][rg] + bias;
      }
    }
  }
  __syncthreads();
  if (final_flag) {
    int row = tid >> 4, c8 = (tid & 15) * 8;
    fx4 t0 = *(const fx4*)&snew[row * 132 + c8];
    fx4 t1 = *(const fx4*)&snew[row * 132 + c8 + 4];
    *(fx4*)(out_final + (long)(rowbase + row) * 128 + c8) = t0;
    *(fx4*)(out_final + (long)(rowbase + row) * 128 + c8 + 4) = t1;
    return;
  }
  // fused next-iter: LN(new slots) -> slots_n + q2
  if (w == 0) {
    float v[32];
    float s = 0.f, s2 = 0.f;
#pragma unroll
    for (int i = 0; i < 32; i++) {
      float t = snew[r * 132 + seg * 32 + i];
      v[i] = t; s += t; s2 += t * t;
    }
    s += __shfl_xor(s, 16, 64);  s += __shfl_xor(s, 32, 64);
    s2 += __shfl_xor(s2, 16, 64); s2 += __shfl_xor(s2, 32, 64);
    float mean = s * 0.0078125f;
    float var = s2 * 0.0078125f - mean * mean;
    float rstd = rsqrtf(var + 1e-5f);
    float* snp = slots_n + (long)(rowbase + r) * 128 + seg * 32;
#pragma unroll
    for (int i = 0; i < 8; i++) {
      fx4 t = {(v[i * 4 + 0] - mean) * rstd, (v[i * 4 + 1] - mean) * rstd,
               (v[i * 4 + 2] - mean) * rstd, (v[i * 4 + 3] - mean) * rstd};
      *(fx4*)(snp + i * 4) = t;
      v[i * 4 + 0] = t.x; v[i * 4 + 1] = t.y; v[i * 4 + 2] = t.z; v[i * 4 + 3] = t.w;
    }
#pragma unroll
    for (int q = 0; q < 4; q++) {
      sx8 t;
#pragma unroll
      for (int j = 0; j < 8; j++) t[j] = (short)f2bf(v[q * 8 + j]);
      *(sx8*)&ynf[(seg * 64 + (r + 16 * q)) * 8] = t;
    }
  }
  __syncthreads();
  {  // q2 GEMM: wave w computes nt = w*2, w*2+1
    fx4 acc2[2];
    acc2[0] = z4; acc2[1] = z4;
#pragma unroll
    for (int ks = 0; ks < 4; ks++) {
      sx8 a = *(const sx8*)&ynf[(ks * 64 + l) * 8];
#pragma unroll
      for (int j = 0; j < 2; j++) {
        int nt = w * 2 + j;
        sx8 bf = *(const sx8*)(wqk_b + (nt * 16 + (l & 15)) * 128 + ks * 32 + (l >> 4) * 8);
        acc2[j] = MFMA(a, bf, acc2[j]);
      }
    }
    int cl = l & 15, rq = (l >> 4) * 4;
#pragma unroll
    for (int j = 0; j < 2; j++) {
      int nt = w * 2 + j;
#pragma unroll
      for (int rg = 0; rg < 4; rg++)
        q2_b[(long)(rowbase + rq + rg) * 128 + nt * 16 + cl] = f2bf(acc2[j][rg]);
    }
  }
}

extern "C" void kernel_launch(void* const* d_in, const int* in_sizes, int n_in,
                              void* d_out, int out_size, void* d_ws, size_t ws_size,
                              hipStream_t stream) {
  (void)in_sizes; (void)n_in; (void)out_size; (void)ws_size;
  const float* x = (const float*)d_in[0];
  const float* noise = (const float*)d_in[1];
  const float* mu = (const float*)d_in[2];
  const float* lsig = (const float*)d_in[3];
  const float* Wq = (const float*)d_in[4];
  const float* Wk = (const float*)d_in[5];
  const float* Wv = (const float*)d_in[6];
  const float* Wih = (const float*)d_in[7];
  const float* Whh = (const float*)d_in[8];
  const float* b_ih = (const float*)d_in[9];
  const float* b_hh = (const float*)d_in[10];
  const float* W1 = (const float*)d_in[11];
  const float* b1 = (const float*)d_in[12];
  const float* W2 = (const float*)d_in[13];
  const float* b2 = (const float*)d_in[14];

  char* ws = (char*)d_ws;
  size_t off = 0;
  auto take = [&](size_t bytes) {
    char* p = ws + off;
    off += (bytes + 255) & ~(size_t)255;
    return p;
  };
  unsigned short* ln16 = (unsigned short*)take(134217728);  // LN(x) bf16 row-major
  float* Wqk = (float*)take(65536);
  float* Wihv = (float*)take(196608);
  unsigned short* wqk_b = (unsigned short*)take(32768);
  unsigned short* wihv_b = (unsigned short*)take(98304);
  unsigned short* whh_b = (unsigned short*)take(98304);
  unsigned short* w1_b = (unsigned short*)take(65536);
  unsigned short* w2_b = (unsigned short*)take(65536);
  float* slots = (float*)take(524288);
  float* slots_n = (float*)take(524288);
  unsigned short* q2_b = (unsigned short*)take(262144);
  float* upd_part = (float*)take(33554432);   // raw partials (B,64,8,128) fp32
  float* sattn_part = (float*)take(262144);   // (B,64,8)

  k_fold<<<256, 256, 0, stream>>>(Wq, Wk, Wih, Wv, Wqk, Wihv);
  k_pack<<<1216, 256, 0, stream>>>(noise, mu, lsig, Wqk, Wihv, Whh, W1, W2,
                                   slots, wqk_b, wihv_b, whh_b, w1_b, w2_b);
  k_slot_pre<<<64, 64, 0, stream>>>(slots, wqk_b, slots_n, q2_b);
  // iter 0: LN fused into the attention pass
  k_attn_first<<<8192, 256, 0, stream>>>(x, ln16, q2_b, upd_part, sattn_part);
  k_slot_post<<<64, 256, 0, stream>>>(upd_part, sattn_part, slots_n, wihv_b, whh_b,
                                      b_ih, b_hh, w1_b, b1, w2_b, b2, wqk_b,
                                      q2_b, (float*)d_out, 0);
  for (int it = 1; it < 3; it++) {
    k_attn<<<8192, 256, 0, stream>>>(ln16, q2_b, upd_part, sattn_part);
    k_slot_post<<<64, 256, 0, stream>>>(upd_part, sattn_part, slots_n, wihv_b, whh_b,
                                        b_ih, b_hh, w1_b, b1, w2_b, b2, wqk_b,
                                        q2_b, (float*)d_out, (it == 2) ? 1 : 0);
  }
}

// Round 8
// 549.290 us; speedup vs baseline: 3.1502x; 1.0804x over previous
//
#include <hip/hip_runtime.h>
#include <math.h>

// B=128, N=4096, Din=128, D=128, S(slots)=8, H=256, 3 iterations.
// Algebraic folds: logits = xn @ q2^T with q2 = slots_n @ Wqk, Wqk = scale*Wq^T@Wk.
// gx = raw @ Wihv^T with raw = attn^T @ xn (per-chunk partials), Wihv = Wih@Wv.
// R0: LN(x) fused into iter-0 attention. R2: MFMA PV with P hi/lo bf16 split.
// R3: transposed logits + per-lane softmax. R4 (reverted): tail-block fusion.
// R6: LDS X-tile, PV B-frags from LDS (killed the global transpose-gather).
// R7: attn blocks now cover 256 rows (4 sub-tiles of 64), double-buffered LDS:
//   loads for sub-tile t+1 issue BEFORE PV(t) so HBM latency hides under LDS/MFMA
//   work; one barrier per sub-tile; PV accumulates across sub-tiles in regs so
//   upd_part shrinks 33.5->8.4 MB and slot_post phase A reverts to the R3 code.
//   Theory: attn passes were ~150us each (5x their HBM floor) from per-block
//   latency serialization (short blocks, dependent loads, no overlap).
// MFMA 16x16x32 bf16 layouts (verified):
//   C/D: col = lane&15, row = (lane>>4)*4 + reg
//   A  : A[m = lane&15][k = (lane>>4)*8 + j]
//   B  : B[k = (lane>>4)*8 + j][n = lane&15]  (row-major [N][K] source)

typedef __attribute__((ext_vector_type(4))) float fx4;
typedef __attribute__((ext_vector_type(8))) short sx8;
typedef __attribute__((ext_vector_type(8))) __bf16 bfx8;

static __device__ __forceinline__ fx4 MFMA(sx8 a, sx8 b, fx4 c) {
  return __builtin_amdgcn_mfma_f32_16x16x32_bf16(
      __builtin_bit_cast(bfx8, a), __builtin_bit_cast(bfx8, b), c, 0, 0, 0);
}

static __device__ __forceinline__ unsigned short f2bf(float f) {
  union { float f; unsigned u; } x; x.f = f;
  unsigned r = x.u + 0x7fffu + ((x.u >> 16) & 1u);  // RNE
  return (unsigned short)(r >> 16);
}
static __device__ __forceinline__ float bf2f(unsigned short u) {
  union { unsigned u; float f; } x; x.u = ((unsigned)u) << 16; return x.f;
}
static __device__ __forceinline__ fx4 ntload4(const float* p) {
  return __builtin_nontemporal_load((const fx4*)p);
}

#define PST 72  // P^T plane row stride (shorts)

// per-lane softmax over 8 slots (transposed-logits layout) + P hi/lo store
static __device__ __forceinline__ void softmax_store(
    fx4 cc, float* satacc, short* ph, short* pl, int nloc, int seg) {
  float m01 = fmaxf(fmaxf(cc[0], cc[1]), fmaxf(cc[2], cc[3]));
  m01 = fmaxf(m01, __shfl_xor(m01, 16, 64));
  float p0 = __expf(cc[0] - m01), p1 = __expf(cc[1] - m01),
        p2 = __expf(cc[2] - m01), p3 = __expf(cc[3] - m01);
  float sl = p0 + p1 + p2 + p3;
  sl += __shfl_xor(sl, 16, 64);
  float inv = 1.f / sl;
  float at0 = p0 * inv + 1e-8f, at1 = p1 * inv + 1e-8f;
  float at2 = p2 * inv + 1e-8f, at3 = p3 * inv + 1e-8f;
  satacc[0] += at0; satacc[1] += at1; satacc[2] += at2; satacc[3] += at3;
  unsigned short h0 = f2bf(at0), h1 = f2bf(at1), h2 = f2bf(at2), h3 = f2bf(at3);
  ph[(seg * 4 + 0) * PST + nloc] = (short)h0;
  ph[(seg * 4 + 1) * PST + nloc] = (short)h1;
  ph[(seg * 4 + 2) * PST + nloc] = (short)h2;
  ph[(seg * 4 + 3) * PST + nloc] = (short)h3;
  pl[(seg * 4 + 0) * PST + nloc] = (short)f2bf(at0 - bf2f(h0));
  pl[(seg * 4 + 1) * PST + nloc] = (short)f2bf(at1 - bf2f(h1));
  pl[(seg * 4 + 2) * PST + nloc] = (short)f2bf(at2 - bf2f(h2));
  pl[(seg * 4 + 3) * PST + nloc] = (short)f2bf(at3 - bf2f(h3));
}

// ---------------- fold: Wqk = scale*Wq^T@Wk (fp32), Wihv = Wih@Wv (fp32) -------------
__global__ __launch_bounds__(256) void k_fold(
    const float* __restrict__ Wq, const float* __restrict__ Wk,
    const float* __restrict__ Wih, const float* __restrict__ Wv,
    float* __restrict__ Wqk, float* __restrict__ Wihv) {
  int idx = blockIdx.x * 256 + threadIdx.x;
  if (idx < 16384) {
    int e = idx >> 7, c = idx & 127;
    float s = 0.f;
#pragma unroll 4
    for (int d = 0; d < 128; d++) s += Wq[d * 128 + e] * Wk[d * 128 + c];
    Wqk[idx] = s * 0.08838834764831845f;
    return;
  }
  idx -= 16384;
  if (idx < 49152) {
    int g = idx >> 7, c = idx & 127;
    float s = 0.f;
#pragma unroll 4
    for (int d = 0; d < 128; d++) s += Wih[g * 128 + d] * Wv[d * 128 + c];
    Wihv[idx] = s;
  }
}

// ---------------- pack: slots init + bf16 weight tables ----------------
__global__ __launch_bounds__(256) void k_pack(
    const float* __restrict__ noise, const float* __restrict__ mu,
    const float* __restrict__ lsig, const float* __restrict__ Wqk,
    const float* __restrict__ Wihv, const float* __restrict__ Whh,
    const float* __restrict__ W1, const float* __restrict__ W2,
    float* __restrict__ slots, unsigned short* __restrict__ wqk_b,
    unsigned short* __restrict__ wihv_b, unsigned short* __restrict__ whh_b,
    unsigned short* __restrict__ w1_b, unsigned short* __restrict__ w2_b) {
  int idx = blockIdx.x * 256 + threadIdx.x;
  if (idx < 131072) {
    int d = idx & 127;
    slots[idx] = mu[d] + expf(lsig[d]) * noise[idx];
    return;
  }
  idx -= 131072;
  if (idx < 16384) {  // wqk_b row-major [n=c][k=e] <- Wqk[e,c]
    wqk_b[idx] = f2bf(Wqk[(idx & 127) * 128 + (idx >> 7)]);
    return;
  }
  idx -= 16384;
  if (idx < 49152) { wihv_b[idx] = f2bf(Wihv[idx]); return; }
  idx -= 49152;
  if (idx < 49152) { whh_b[idx] = f2bf(Whh[idx]); return; }
  idx -= 49152;
  if (idx < 32768) { w1_b[idx] = f2bf(W1[idx]); return; }
  idx -= 32768;
  w2_b[idx] = f2bf(W2[idx]);
}

// ---------------- iter0 only: LN(slots) + q2 = slots_n @ Wqk ----------------
__global__ __launch_bounds__(64) void k_slot_pre(
    const float* __restrict__ slots, const unsigned short* __restrict__ wqk_b,
    float* __restrict__ slots_n, unsigned short* __restrict__ q2_b) {
  __shared__ __align__(16) short xf[4 * 64 * 8];
  int l = threadIdx.x;
  int r = l & 15, seg = l >> 4;
  long rowbase = (long)blockIdx.x * 16;
  {
    const float* xp = slots + (rowbase + r) * 128 + seg * 32;
    float* snp = slots_n + (rowbase + r) * 128 + seg * 32;
    float v[32];
    float s = 0.f, s2 = 0.f;
#pragma unroll
    for (int i = 0; i < 8; i++) {
      fx4 t = *(const fx4*)(xp + i * 4);
      v[i * 4 + 0] = t.x; v[i * 4 + 1] = t.y; v[i * 4 + 2] = t.z; v[i * 4 + 3] = t.w;
      s += t.x + t.y + t.z + t.w;
      s2 += t.x * t.x + t.y * t.y + t.z * t.z + t.w * t.w;
    }
    s += __shfl_xor(s, 16, 64);  s += __shfl_xor(s, 32, 64);
    s2 += __shfl_xor(s2, 16, 64); s2 += __shfl_xor(s2, 32, 64);
    float mean = s * 0.0078125f;
    float var = s2 * 0.0078125f - mean * mean;
    float rstd = rsqrtf(var + 1e-5f);
#pragma unroll
    for (int i = 0; i < 8; i++) {
      fx4 t = {(v[i * 4 + 0] - mean) * rstd, (v[i * 4 + 1] - mean) * rstd,
               (v[i * 4 + 2] - mean) * rstd, (v[i * 4 + 3] - mean) * rstd};
      *(fx4*)(snp + i * 4) = t;
      v[i * 4 + 0] = t.x; v[i * 4 + 1] = t.y; v[i * 4 + 2] = t.z; v[i * 4 + 3] = t.w;
    }
#pragma unroll
    for (int q = 0; q < 4; q++) {
      sx8 t;
#pragma unroll
      for (int j = 0; j < 8; j++) t[j] = (short)f2bf(v[q * 8 + j]);
      *(sx8*)&xf[(seg * 64 + (r + 16 * q)) * 8] = t;
    }
  }
  __syncthreads();
  const fx4 z4 = {0.f, 0.f, 0.f, 0.f};
  fx4 acc[8];
#pragma unroll
  for (int nt = 0; nt < 8; nt++) acc[nt] = z4;
#pragma unroll
  for (int ks = 0; ks < 4; ks++) {
    sx8 a = *(const sx8*)&xf[(ks * 64 + l) * 8];
#pragma unroll
    for (int nt = 0; nt < 8; nt++) {
      sx8 bfr = *(const sx8*)(wqk_b + (nt * 16 + (l & 15)) * 128 + ks * 32 + (l >> 4) * 8);
      acc[nt] = MFMA(a, bfr, acc[nt]);
    }
  }
  int cl = l & 15, rq = (l >> 4) * 4;
#pragma unroll
  for (int nt = 0; nt < 8; nt++)
#pragma unroll
    for (int rg = 0; rg < 4; rg++)
      q2_b[(rowbase + rq + rg) * 128 + nt * 16 + cl] = f2bf(acc[nt][rg]);
}

// ---------------- attention iters 1-2: 256-row pipelined blocks ----------------
// grid = 128 b * 16 chunks = 2048 blocks, 256 thr. 4 sub-tiles of 64 rows,
// double-buffered LDS X-tile + P-planes; loads(t+1) issue before PV(t).
__global__ __launch_bounds__(256, 3) void k_attn(
    const unsigned short* __restrict__ ln16, const unsigned short* __restrict__ q2b,
    float* __restrict__ upd_part, float* __restrict__ sattn_part) {
  __shared__ __align__(16) short xlds[2][64 * 128];       // 2 x 16 KB, swizzled
  __shared__ __align__(16) short pplane[2][2][16 * PST];  // P^T hi/lo x 2 bufs
  __shared__ float sattnbuf[32];
  int tid = threadIdx.x, w = tid >> 6, l = tid & 63;
  int b = blockIdx.x >> 4, c = blockIdx.x & 15;
  int nr = l & 15, seg = l >> 4, qd = seg * 8;
  int nloc = w * 16 + nr;
  const unsigned short* xt = ln16 + ((long)b * 4096 + c * 256 + nloc) * 128;
  sx8 qf[4];
#pragma unroll
  for (int ks = 0; ks < 4; ks++) {
    if (nr < 8) {
      qf[ks] = *(const sx8*)(q2b + ((long)b * 8 + nr) * 128 + ks * 32 + qd);
    } else {
      sx8 t;
#pragma unroll
      for (int j = 0; j < 8; j++) t[j] = 0;
      qf[ks] = t;
    }
  }
  const fx4 z4 = {0.f, 0.f, 0.f, 0.f};
  float satacc[4] = {0.f, 0.f, 0.f, 0.f};
  fx4 acc[2];
  acc[0] = z4; acc[1] = z4;
  int qsw = ((nloc >> 3) & 3) << 5;
  sx8 xr[4];
#pragma unroll
  for (int ks = 0; ks < 4; ks++) xr[ks] = *(const sx8*)(xt + ks * 32 + qd);
  {  // stage sub-tile 0
    fx4 cc = z4;
#pragma unroll
    for (int ks = 0; ks < 4; ks++) {
      *(sx8*)&xlds[0][(nloc * 256 + ((ks * 64 + seg * 16) ^ qsw)) >> 1] = xr[ks];
      cc = MFMA(qf[ks], xr[ks], cc);
    }
    softmax_store(cc, satacc, &pplane[0][0][0], &pplane[0][1][0], nloc, seg);
  }
  __syncthreads();
#pragma unroll
  for (int t = 0; t < 4; t++) {
    if (t < 3) {  // issue next sub-tile loads before PV
#pragma unroll
      for (int ks = 0; ks < 4; ks++)
        xr[ks] = *(const sx8*)(xt + (t + 1) * 8192 + ks * 32 + qd);
    }
    // PV from buf t&1: raw[s][d] += sum_n P^T[s][n]*X[n][d]
#pragma unroll
    for (int nt2 = 0; nt2 < 2; nt2++) {
      int cols = ((((w * 2 + nt2) * 16 + nr) * 2) ^ (seg << 5)) >> 1;
#pragma unroll
      for (int ks2 = 0; ks2 < 2; ks2++) {
        sx8 bfr;
#pragma unroll
        for (int j = 0; j < 8; j++)
          bfr[j] = xlds[t & 1][(ks2 * 32 + seg * 8 + j) * 128 + cols];
        sx8 pah = *(const sx8*)&pplane[t & 1][0][nr * PST + ks2 * 32 + seg * 8];
        sx8 pal = *(const sx8*)&pplane[t & 1][1][nr * PST + ks2 * 32 + seg * 8];
        acc[nt2] = MFMA(pah, bfr, acc[nt2]);
        acc[nt2] = MFMA(pal, bfr, acc[nt2]);
      }
    }
    if (t < 3) {  // stage sub-tile t+1 into the other buffer
      fx4 cc = z4;
#pragma unroll
      for (int ks = 0; ks < 4; ks++) {
        *(sx8*)&xlds[(t + 1) & 1][(nloc * 256 + ((ks * 64 + seg * 16) ^ qsw)) >> 1] = xr[ks];
        cc = MFMA(qf[ks], xr[ks], cc);
      }
      softmax_store(cc, satacc, &pplane[(t + 1) & 1][0][0], &pplane[(t + 1) & 1][1][0],
                    nloc, seg);
      __syncthreads();
    }
  }
  // final: upd write (per-wave disjoint d-tiles) + sat reduce
  if (seg < 2) {
    size_t ubase = (size_t)(b * 16 + c) * 1024;
#pragma unroll
    for (int nt2 = 0; nt2 < 2; nt2++)
#pragma unroll
      for (int rg = 0; rg < 4; rg++)
        upd_part[ubase + (seg * 4 + rg) * 128 + (w * 2 + nt2) * 16 + nr] = acc[nt2][rg];
  }
  {
    float v0 = satacc[0], v1 = satacc[1], v2 = satacc[2], v3 = satacc[3];
#pragma unroll
    for (int m = 1; m < 16; m <<= 1) {
      v0 += __shfl_xor(v0, m, 64); v1 += __shfl_xor(v1, m, 64);
      v2 += __shfl_xor(v2, m, 64); v3 += __shfl_xor(v3, m, 64);
    }
    if (nr == 0 && seg < 2) {
      sattnbuf[w * 8 + seg * 4 + 0] = v0;
      sattnbuf[w * 8 + seg * 4 + 1] = v1;
      sattnbuf[w * 8 + seg * 4 + 2] = v2;
      sattnbuf[w * 8 + seg * 4 + 3] = v3;
    }
  }
  __syncthreads();
  if (tid < 8)
    sattn_part[(b * 16 + c) * 8 + tid] =
        sattnbuf[tid] + sattnbuf[8 + tid] + sattnbuf[16 + tid] + sattnbuf[24 + tid];
}

// ---------------- iter-0 attention: fused LN(x), 256-row pipelined blocks ----------
__global__ __launch_bounds__(256, 3) void k_attn_first(
    const float* __restrict__ x, unsigned short* __restrict__ ln16,
    const unsigned short* __restrict__ q2b,
    float* __restrict__ upd_part, float* __restrict__ sattn_part) {
  __shared__ __align__(16) short xlds[2][64 * 128];
  __shared__ __align__(16) short pplane[2][2][16 * PST];
  __shared__ float sattnbuf[32];
  int tid = threadIdx.x, w = tid >> 6, l = tid & 63;
  int b = blockIdx.x >> 4, c = blockIdx.x & 15;
  int nr = l & 15, seg = l >> 4, qd = seg * 8;
  int nloc = w * 16 + nr;
  long rowg = (long)b * 4096 + c * 256 + nloc;
  const float* xs = x + rowg * 128;
  unsigned short* xo = ln16 + rowg * 128;
  sx8 qf[4];
#pragma unroll
  for (int ks = 0; ks < 4; ks++) {
    if (nr < 8) {
      qf[ks] = *(const sx8*)(q2b + ((long)b * 8 + nr) * 128 + ks * 32 + qd);
    } else {
      sx8 t;
#pragma unroll
      for (int j = 0; j < 8; j++) t[j] = 0;
      qf[ks] = t;
    }
  }
  const fx4 z4 = {0.f, 0.f, 0.f, 0.f};
  float satacc[4] = {0.f, 0.f, 0.f, 0.f};
  fx4 acc[2];
  acc[0] = z4; acc[1] = z4;
  int qsw = ((nloc >> 3) & 3) << 5;
  fx4 vn[8];
#pragma unroll
  for (int i = 0; i < 8; i++) vn[i] = ntload4(xs + (i >> 1) * 32 + qd + (i & 1) * 4);
  {  // stage sub-tile 0: LN + ln16 write + LDS + logits
    float sm = 0.f, s2 = 0.f;
#pragma unroll
    for (int i = 0; i < 8; i++) {
      fx4 t = vn[i];
      sm += t.x + t.y + t.z + t.w;
      s2 += t.x * t.x + t.y * t.y + t.z * t.z + t.w * t.w;
    }
    sm += __shfl_xor(sm, 16, 64);  sm += __shfl_xor(sm, 32, 64);
    s2 += __shfl_xor(s2, 16, 64);  s2 += __shfl_xor(s2, 32, 64);
    float mean = sm * 0.0078125f;
    float rstd = rsqrtf(s2 * 0.0078125f - mean * mean + 1e-5f);
    fx4 cc = z4;
#pragma unroll
    for (int ks = 0; ks < 4; ks++) {
      sx8 t;
#pragma unroll
      for (int j = 0; j < 8; j++)
        t[j] = (short)f2bf((vn[ks * 2 + (j >> 2)][j & 3] - mean) * rstd);
      *(sx8*)(xo + ks * 32 + qd) = t;
      *(sx8*)&xlds[0][(nloc * 256 + ((ks * 64 + seg * 16) ^ qsw)) >> 1] = t;
      cc = MFMA(qf[ks], t, cc);
    }
    softmax_store(cc, satacc, &pplane[0][0][0], &pplane[0][1][0], nloc, seg);
  }
  __syncthreads();
#pragma unroll
  for (int t = 0; t < 4; t++) {
    if (t < 3) {
#pragma unroll
      for (int i = 0; i < 8; i++)
        vn[i] = ntload4(xs + (t + 1) * 8192 + (i >> 1) * 32 + qd + (i & 1) * 4);
    }
#pragma unroll
    for (int nt2 = 0; nt2 < 2; nt2++) {
      int cols = ((((w * 2 + nt2) * 16 + nr) * 2) ^ (seg << 5)) >> 1;
#pragma unroll
      for (int ks2 = 0; ks2 < 2; ks2++) {
        sx8 bfr;
#pragma unroll
        for (int j = 0; j < 8; j++)
          bfr[j] = xlds[t & 1][(ks2 * 32 + seg * 8 + j) * 128 + cols];
        sx8 pah = *(const sx8*)&pplane[t & 1][0][nr * PST + ks2 * 32 + seg * 8];
        sx8 pal = *(const sx8*)&pplane[t & 1][1][nr * PST + ks2 * 32 + seg * 8];
        acc[nt2] = MFMA(pah, bfr, acc[nt2]);
        acc[nt2] = MFMA(pal, bfr, acc[nt2]);
      }
    }
    if (t < 3) {
      float sm = 0.f, s2 = 0.f;
#pragma unroll
      for (int i = 0; i < 8; i++) {
        fx4 tt = vn[i];
        sm += tt.x + tt.y + tt.z + tt.w;
        s2 += tt.x * tt.x + tt.y * tt.y + tt.z * tt.z + tt.w * tt.w;
      }
      sm += __shfl_xor(sm, 16, 64);  sm += __shfl_xor(sm, 32, 64);
      s2 += __shfl_xor(s2, 16, 64);  s2 += __shfl_xor(s2, 32, 64);
      float mean = sm * 0.0078125f;
      float rstd = rsqrtf(s2 * 0.0078125f - mean * mean + 1e-5f);
      fx4 cc = z4;
#pragma unroll
      for (int ks = 0; ks < 4; ks++) {
        sx8 tt;
#pragma unroll
        for (int j = 0; j < 8; j++)
          tt[j] = (short)f2bf((vn[ks * 2 + (j >> 2)][j & 3] - mean) * rstd);
        *(sx8*)(xo + (t + 1) * 8192 + ks * 32 + qd) = tt;
        *(sx8*)&xlds[(t + 1) & 1][(nloc * 256 + ((ks * 64 + seg * 16) ^ qsw)) >> 1] = tt;
        cc = MFMA(qf[ks], tt, cc);
      }
      softmax_store(cc, satacc, &pplane[(t + 1) & 1][0][0], &pplane[(t + 1) & 1][1][0],
                    nloc, seg);
      __syncthreads();
    }
  }
  if (seg < 2) {
    size_t ubase = (size_t)(b * 16 + c) * 1024;
#pragma unroll
    for (int nt2 = 0; nt2 < 2; nt2++)
#pragma unroll
      for (int rg = 0; rg < 4; rg++)
        upd_part[ubase + (seg * 4 + rg) * 128 + (w * 2 + nt2) * 16 + nr] = acc[nt2][rg];
  }
  {
    float v0 = satacc[0], v1 = satacc[1], v2 = satacc[2], v3 = satacc[3];
#pragma unroll
    for (int m = 1; m < 16; m <<= 1) {
      v0 += __shfl_xor(v0, m, 64); v1 += __shfl_xor(v1, m, 64);
      v2 += __shfl_xor(v2, m, 64); v3 += __shfl_xor(v3, m, 64);
    }
    if (nr == 0 && seg < 2) {
      sattnbuf[w * 8 + seg * 4 + 0] = v0;
      sattnbuf[w * 8 + seg * 4 + 1] = v1;
      sattnbuf[w * 8 + seg * 4 + 2] = v2;
      sattnbuf[w * 8 + seg * 4 + 3] = v3;
    }
  }
  __syncthreads();
  if (tid < 8)
    sattn_part[(b * 16 + c) * 8 + tid] =
        sattnbuf[tid] + sattnbuf[8 + tid] + sattnbuf[16 + tid] + sattnbuf[24 + tid];
}

// ---------------- GRU + MLP (+ fused next-iter LN+q2) ----------------
// 64 blocks x 256 thr; 16 slot-rows (2 batches) per block. 16 chunks/batch.
__global__ __launch_bounds__(256) void k_slot_post(
    const float* __restrict__ upd_part, const float* __restrict__ sattn_part,
    float* __restrict__ slots_n,
    const unsigned short* __restrict__ wihv_b, const unsigned short* __restrict__ whh_b,
    const float* __restrict__ b_ih, const float* __restrict__ b_hh,
    const unsigned short* __restrict__ w1_b, const float* __restrict__ b1,
    const unsigned short* __restrict__ w2_b, const float* __restrict__ b2,
    const unsigned short* __restrict__ wqk_b,
    unsigned short* __restrict__ q2_b, float* __restrict__ out_final, int final_flag) {
  __shared__ __align__(16) char smem[78336];
  float* gx = (float*)smem;                  // 24576 (16x384)
  float* gh = (float*)(smem + 24576);        // 24576
  float* xred = gx;                          // phase A overlay: 4*2048 floats
  short* xfr = (short*)(smem + 49152);       // 4096
  short* hfr = (short*)(smem + 53248);       // 4096
  short* ynf = (short*)(smem + 57344);       // 4096
  short* y1f = (short*)(smem + 61440);       // 8192
  float* snew = (float*)(smem + 69632);      // 16*132*4 = 8448
  float* satred = (float*)(smem + 78080);    // 256
  int tid = threadIdx.x, w = tid >> 6, l = tid & 63;
  int rowbase = blockIdx.x * 16;
  int r = l & 15, seg = l >> 4;
  {  // phase A: every wave reduces 4 chunks of raw partials
    int row = rowbase + r;
    int bb = row >> 3, ss = row & 7;
    float a[32];
#pragma unroll
    for (int i = 0; i < 32; i++) a[i] = 0.f;
    float satsum = 0.f;
#pragma unroll
    for (int ci = 0; ci < 4; ci++) {
      int ch = bb * 16 + w * 4 + ci;
      const float* up = upd_part + (size_t)ch * 1024 + ss * 128 + seg * 32;
#pragma unroll
      for (int i = 0; i < 8; i++) {
        fx4 t = *(const fx4*)(up + i * 4);
        a[i * 4 + 0] += t.x; a[i * 4 + 1] += t.y; a[i * 4 + 2] += t.z; a[i * 4 + 3] += t.w;
      }
      satsum += sattn_part[ch * 8 + ss];
    }
#pragma unroll
    for (int i = 0; i < 8; i++) {
      fx4 t = {a[i * 4], a[i * 4 + 1], a[i * 4 + 2], a[i * 4 + 3]};
      *(fx4*)&xred[w * 2048 + r * 128 + seg * 32 + i * 4] = t;
    }
    if (seg == 0) satred[w * 16 + r] = satsum;
  }
  __syncthreads();
  if (w == 0) {  // combine -> raw_scaled A-frags
    float inv = 1.f / (satred[r] + satred[16 + r] + satred[32 + r] + satred[48 + r]);
    float a[32];
#pragma unroll
    for (int i = 0; i < 8; i++) {
      fx4 t = *(const fx4*)&xred[r * 128 + seg * 32 + i * 4];
      fx4 t1 = *(const fx4*)&xred[2048 + r * 128 + seg * 32 + i * 4];
      fx4 t2 = *(const fx4*)&xred[4096 + r * 128 + seg * 32 + i * 4];
      fx4 t3 = *(const fx4*)&xred[6144 + r * 128 + seg * 32 + i * 4];
      t = t + t1 + t2 + t3;
      a[i * 4 + 0] = t.x * inv; a[i * 4 + 1] = t.y * inv;
      a[i * 4 + 2] = t.z * inv; a[i * 4 + 3] = t.w * inv;
    }
#pragma unroll
    for (int q = 0; q < 4; q++) {
      sx8 t;
#pragma unroll
      for (int j = 0; j < 8; j++) t[j] = (short)f2bf(a[q * 8 + j]);
      *(sx8*)&xfr[(seg * 64 + (r + 16 * q)) * 8] = t;
    }
  } else if (w == 1) {  // h = slots_n -> A-frags
    const float* hp = slots_n + (long)(rowbase + r) * 128 + seg * 32;
#pragma unroll
    for (int q = 0; q < 4; q++) {
      fx4 t0 = *(const fx4*)(hp + q * 8);
      fx4 t1 = *(const fx4*)(hp + q * 8 + 4);
      sx8 t;
      t[0] = (short)f2bf(t0.x); t[1] = (short)f2bf(t0.y);
      t[2] = (short)f2bf(t0.z); t[3] = (short)f2bf(t0.w);
      t[4] = (short)f2bf(t1.x); t[5] = (short)f2bf(t1.y);
      t[6] = (short)f2bf(t1.z); t[7] = (short)f2bf(t1.w);
      *(sx8*)&hfr[(seg * 64 + (r + 16 * q)) * 8] = t;
    }
  }
  __syncthreads();
  const fx4 z4 = {0.f, 0.f, 0.f, 0.f};
  {  // GEMM1: gx = raw_scaled@Wihv^T, gh = h@Whh^T
    fx4 ax[6], ah[6];
#pragma unroll
    for (int j = 0; j < 6; j++) { ax[j] = z4; ah[j] = z4; }
#pragma unroll
    for (int ks = 0; ks < 4; ks++) {
      sx8 a_x = *(const sx8*)&xfr[(ks * 64 + l) * 8];
      sx8 a_h = *(const sx8*)&hfr[(ks * 64 + l) * 8];
#pragma unroll
      for (int j = 0; j < 6; j++) {
        int nt = w * 6 + j;
        sx8 bx = *(const sx8*)(wihv_b + (nt * 16 + (l & 15)) * 128 + ks * 32 + (l >> 4) * 8);
        sx8 bh = *(const sx8*)(whh_b + (nt * 16 + (l & 15)) * 128 + ks * 32 + (l >> 4) * 8);
        ax[j] = MFMA(a_x, bx, ax[j]);
        ah[j] = MFMA(a_h, bh, ah[j]);
      }
    }
#pragma unroll
    for (int j = 0; j < 6; j++) {
      int col = (w * 6 + j) * 16 + (l & 15);
#pragma unroll
      for (int rg = 0; rg < 4; rg++) {
        int row = (l >> 4) * 4 + rg;
        gx[row * 384 + col] = ax[j][rg];
        gh[row * 384 + col] = ah[j][rg];
      }
    }
  }
  __syncthreads();
  {  // GRU gates
    int row = tid >> 4, j0 = (tid & 15) * 8;
#pragma unroll
    for (int j = j0; j < j0 + 8; j++) {
      float xr = gx[row * 384 + j] + b_ih[j];
      float xz = gx[row * 384 + 128 + j] + b_ih[128 + j];
      float xn = gx[row * 384 + 256 + j] + b_ih[256 + j];
      float hr = gh[row * 384 + j] + b_hh[j];
      float hz = gh[row * 384 + 128 + j] + b_hh[128 + j];
      float hn = gh[row * 384 + 256 + j] + b_hh[256 + j];
      float rr = 1.f / (1.f + __expf(-(xr + hr)));
      float zz = 1.f / (1.f + __expf(-(xz + hz)));
      float nn = tanhf(xn + rr * hn);
      float h = slots_n[(long)(rowbase + row) * 128 + j];
      snew[row * 132 + j] = (1.f - zz) * nn + zz * h;
    }
  }
  __syncthreads();
  if (w == 0) {  // LN(snew) -> ynf A-frags
    float v[32];
    float s = 0.f, s2 = 0.f;
#pragma unroll
    for (int i = 0; i < 32; i++) {
      float t = snew[r * 132 + seg * 32 + i];
      v[i] = t; s += t; s2 += t * t;
    }
    s += __shfl_xor(s, 16, 64);  s += __shfl_xor(s, 32, 64);
    s2 += __shfl_xor(s2, 16, 64); s2 += __shfl_xor(s2, 32, 64);
    float mean = s * 0.0078125f;
    float var = s2 * 0.0078125f - mean * mean;
    float rstd = rsqrtf(var + 1e-5f);
#pragma unroll
    for (int q = 0; q < 4; q++) {
      sx8 t;
#pragma unroll
      for (int j = 0; j < 8; j++) t[j] = (short)f2bf((v[q * 8 + j] - mean) * rstd);
      *(sx8*)&ynf[(seg * 64 + (r + 16 * q)) * 8] = t;
    }
  }
  __syncthreads();
  {  // GEMM2: y1 = relu(LN@W1^T + b1) -> A-frags for GEMM3
    fx4 y[4];
#pragma unroll
    for (int j = 0; j < 4; j++) y[j] = z4;
#pragma unroll
    for (int ks = 0; ks < 4; ks++) {
      sx8 a = *(const sx8*)&ynf[(ks * 64 + l) * 8];
#pragma unroll
      for (int j = 0; j < 4; j++) {
        int nt = w * 4 + j;
        sx8 bf = *(const sx8*)(w1_b + (nt * 16 + (l & 15)) * 128 + ks * 32 + (l >> 4) * 8);
        y[j] = MFMA(a, bf, y[j]);
      }
    }
#pragma unroll
    for (int j = 0; j < 4; j++) {
      int col = (w * 4 + j) * 16 + (l & 15);
      float bias = b1[col];
      int ks3 = col >> 5, qq = (col >> 3) & 3, jj = col & 7;
#pragma unroll
      for (int rg = 0; rg < 4; rg++) {
        float val = fmaxf(y[j][rg] + bias, 0.f);
        int m = (l >> 4) * 4 + rg;
        y1f[(ks3 * 64 + m + 16 * qq) * 8 + jj] = (short)f2bf(val);
      }
    }
  }
  __syncthreads();
  {  // GEMM3: snew += y1@W2^T + b2
    fx4 zz2[2];
    zz2[0] = z4; zz2[1] = z4;
#pragma unroll
    for (int ks = 0; ks < 8; ks++) {
      sx8 a = *(const sx8*)&y1f[(ks * 64 + l) * 8];
#pragma unroll
      for (int j = 0; j < 2; j++) {
        sx8 bf = *(const sx8*)(w2_b + ((w * 2 + j) * 16 + (l & 15)) * 256 + ks * 32 + (l >> 4) * 8);
        zz2[j] = MFMA(a, bf, zz2[j]);
      }
    }
#pragma unroll
    for (int j = 0; j < 2; j++) {
      int col = (w * 2 + j) * 16 + (l & 15);
      float bias = b2[col];
#pragma unroll
      for (int rg = 0; rg < 4; rg++) {
        int row = (l >> 4) * 4 + rg;
        snew[row * 132 + col] += zz2[j][rg] + bias;
      }
    }
  }
  __syncthreads();
  if (final_flag) {
    int row = tid >> 4, c8 = (tid & 15) * 8;
    fx4 t0 = *(const fx4*)&snew[row * 132 + c8];
    fx4 t1 = *(const fx4*)&snew[row * 132 + c8 + 4];
    *(fx4*)(out_final + (long)(rowbase + row) * 128 + c8) = t0;
    *(fx4*)(out_final + (long)(rowbase + row) * 128 + c8 + 4) = t1;
    return;
  }
  // fused next-iter: LN(new slots) -> slots_n + q2
  if (w == 0) {
    float v[32];
    float s = 0.f, s2 = 0.f;
#pragma unroll
    for (int i = 0; i < 32; i++) {
      float t = snew[r * 132 + seg * 32 + i];
      v[i] = t; s += t; s2 += t * t;
    }
    s += __shfl_xor(s, 16, 64);  s += __shfl_xor(s, 32, 64);
    s2 += __shfl_xor(s2, 16, 64); s2 += __shfl_xor(s2, 32, 64);
    float mean = s * 0.0078125f;
    float var = s2 * 0.0078125f - mean * mean;
    float rstd = rsqrtf(var + 1e-5f);
    float* snp = slots_n + (long)(rowbase + r) * 128 + seg * 32;
#pragma unroll
    for (int i = 0; i < 8; i++) {
      fx4 t = {(v[i * 4 + 0] - mean) * rstd, (v[i * 4 + 1] - mean) * rstd,
               (v[i * 4 + 2] - mean) * rstd, (v[i * 4 + 3] - mean) * rstd};
      *(fx4*)(snp + i * 4) = t;
      v[i * 4 + 0] = t.x; v[i * 4 + 1] = t.y; v[i * 4 + 2] = t.z; v[i * 4 + 3] = t.w;
    }
#pragma unroll
    for (int q = 0; q < 4; q++) {
      sx8 t;
#pragma unroll
      for (int j = 0; j < 8; j++) t[j] = (short)f2bf(v[q * 8 + j]);
      *(sx8*)&ynf[(seg * 64 + (r + 16 * q)) * 8] = t;
    }
  }
  __syncthreads();
  {  // q2 GEMM: wave w computes nt = w*2, w*2+1
    fx4 acc2[2];
    acc2[0] = z4; acc2[1] = z4;
#pragma unroll
    for (int ks = 0; ks < 4; ks++) {
      sx8 a = *(const sx8*)&ynf[(ks * 64 + l) * 8];
#pragma unroll
      for (int j = 0; j < 2; j++) {
        int nt = w * 2 + j;
        sx8 bf = *(const sx8*)(wqk_b + (nt * 16 + (l & 15)) * 128 + ks * 32 + (l >> 4) * 8);
        acc2[j] = MFMA(a, bf, acc2[j]);
      }
    }
    int cl = l & 15, rq = (l >> 4) * 4;
#pragma unroll
    for (int j = 0; j < 2; j++) {
      int nt = w * 2 + j;
#pragma unroll
      for (int rg = 0; rg < 4; rg++)
        q2_b[(long)(rowbase + rq + rg) * 128 + nt * 16 + cl] = f2bf(acc2[j][rg]);
    }
  }
}

extern "C" void kernel_launch(void* const* d_in, const int* in_sizes, int n_in,
                              void* d_out, int out_size, void* d_ws, size_t ws_size,
                              hipStream_t stream) {
  (void)in_sizes; (void)n_in; (void)out_size; (void)ws_size;
  const float* x = (const float*)d_in[0];
  const float* noise = (const float*)d_in[1];
  const float* mu = (const float*)d_in[2];
  const float* lsig = (const float*)d_in[3];
  const float* Wq = (const float*)d_in[4];
  const float* Wk = (const float*)d_in[5];
  const float* Wv = (const float*)d_in[6];
  const float* Wih = (const float*)d_in[7];
  const float* Whh = (const float*)d_in[8];
  const float* b_ih = (const float*)d_in[9];
  const float* b_hh = (const float*)d_in[10];
  const float* W1 = (const float*)d_in[11];
  const float* b1 = (const float*)d_in[12];
  const float* W2 = (const float*)d_in[13];
  const float* b2 = (const float*)d_in[14];

  char* ws = (char*)d_ws;
  size_t off = 0;
  auto take = [&](size_t bytes) {
    char* p = ws + off;
    off += (bytes + 255) & ~(size_t)255;
    return p;
  };
  unsigned short* ln16 = (unsigned short*)take(134217728);  // LN(x) bf16 row-major
  float* Wqk = (float*)take(65536);
  float* Wihv = (float*)take(196608);
  unsigned short* wqk_b = (unsigned short*)take(32768);
  unsigned short* wihv_b = (unsigned short*)take(98304);
  unsigned short* whh_b = (unsigned short*)take(98304);
  unsigned short* w1_b = (unsigned short*)take(65536);
  unsigned short* w2_b = (unsigned short*)take(65536);
  float* slots = (float*)take(524288);
  float* slots_n = (float*)take(524288);
  unsigned short* q2_b = (unsigned short*)take(262144);
  float* upd_part = (float*)take(8388608);    // raw partials (B,16,8,128) fp32
  float* sattn_part = (float*)take(65536);

  k_fold<<<256, 256, 0, stream>>>(Wq, Wk, Wih, Wv, Wqk, Wihv);
  k_pack<<<1216, 256, 0, stream>>>(noise, mu, lsig, Wqk, Wihv, Whh, W1, W2,
                                   slots, wqk_b, wihv_b, whh_b, w1_b, w2_b);
  k_slot_pre<<<64, 64, 0, stream>>>(slots, wqk_b, slots_n, q2_b);
  // iter 0: LN fused into the attention pass
  k_attn_first<<<2048, 256, 0, stream>>>(x, ln16, q2_b, upd_part, sattn_part);
  k_slot_post<<<64, 256, 0, stream>>>(upd_part, sattn_part, slots_n, wihv_b, whh_b,
                                      b_ih, b_hh, w1_b, b1, w2_b, b2, wqk_b,
                                      q2_b, (float*)d_out, 0);
  for (int it = 1; it < 3; it++) {
    k_attn<<<2048, 256, 0, stream>>>(ln16, q2_b, upd_part, sattn_part);
    k_slot_post<<<64, 256, 0, stream>>>(upd_part, sattn_part, slots_n, wihv_b, whh_b,
                                        b_ih, b_hh, w1_b, b1, w2_b, b2, wqk_b,
                                        q2_b, (float*)d_out, (it == 2) ? 1 : 0);
  }
}